// Round 19
// baseline (462.854 us; speedup 1.0000x reference)
//
#include <hip/hip_runtime.h>
#include <hip/hip_bf16.h>
#include <stdint.h>

typedef __attribute__((ext_vector_type(8))) __bf16 bf16x8;
typedef __attribute__((ext_vector_type(4))) __bf16 bf16x4;
typedef __attribute__((ext_vector_type(4))) float f32x4;
typedef __attribute__((ext_vector_type(16))) float f32x16;
typedef __attribute__((ext_vector_type(4))) unsigned int u32x4;

typedef const __attribute__((address_space(1))) void* gas_ptr;
typedef __attribute__((address_space(3))) void* las_ptr;

static __device__ __forceinline__ void gload_lds16(const void* g, void* l) {
  __builtin_amdgcn_global_load_lds((gas_ptr)g, (las_ptr)l, 16, 0, 0);
}

static __device__ __forceinline__ unsigned int cvt_pk(float lo, float hi) {
  unsigned int r;
  asm("v_cvt_pk_bf16_f32 %0, %1, %2" : "=v"(r) : "v"(lo), "v"(hi));
  return r;
}

static __device__ __forceinline__ bf16x8 pack_frag(unsigned int a, unsigned int b,
                                                   unsigned int c, unsigned int d) {
  u32x4 t = {a, b, c, d};
  return __builtin_bit_cast(bf16x8, t);
}

static __device__ __forceinline__ void vm4() {
  asm volatile("s_waitcnt vmcnt(4)" ::: "memory");
}
static __device__ __forceinline__ void vm6() {
  asm volatile("s_waitcnt vmcnt(6)" ::: "memory");
}
static __device__ __forceinline__ void vm0() {
  asm volatile("s_waitcnt vmcnt(0)" ::: "memory");
}
static __device__ __forceinline__ void lgkm0sb() {
  asm volatile("s_waitcnt lgkmcnt(0)" ::: "memory");
  __builtin_amdgcn_sched_barrier(0);
}
static __device__ __forceinline__ void bar() {
  asm volatile("" ::: "memory");
  __builtin_amdgcn_s_barrier();
  asm volatile("" ::: "memory");
}

// ---------------- generic transpose + fp32->bf16 ----------------
__global__ void transpose_cvt(const float* __restrict__ in, __bf16* __restrict__ out,
                              int R, int S) {
  __shared__ float t[32][33];
  int tx = threadIdx.x, ty = threadIdx.y;
  int r0 = blockIdx.y * 32, s0 = blockIdx.x * 32;
#pragma unroll
  for (int i = 0; i < 4; ++i) {
    int r = r0 + ty + i * 8;
    if (r < R && (s0 + tx) < S) t[ty + i * 8][tx] = in[(size_t)r * S + s0 + tx];
  }
  __syncthreads();
#pragma unroll
  for (int i = 0; i < 4; ++i) {
    int s = s0 + ty + i * 8;
    if (s < S && (r0 + tx) < R) out[(size_t)s * R + r0 + tx] = (__bf16)t[tx][ty + i * 8];
  }
}

// Wq/Wk/Wv [H=16][C=1024][HS=64] -> WqkvT bf16 [3*1024 rows][1024 cols]
__global__ void qkv_repack(const float* __restrict__ Wq, const float* __restrict__ Wk,
                           const float* __restrict__ Wv, __bf16* __restrict__ outT) {
  __shared__ float t[32][33];
  int z = blockIdx.z, sel = z >> 4, h = z & 15;
  const float* in = (sel == 0 ? Wq : sel == 1 ? Wk : Wv) + (size_t)h * 1024 * 64;
  __bf16* out = outT + (size_t)(sel * 1024 + h * 64) * 1024;
  int tx = threadIdx.x, ty = threadIdx.y;
  int r0 = blockIdx.y * 32, s0 = blockIdx.x * 32;
#pragma unroll
  for (int i = 0; i < 4; ++i)
    t[ty + i * 8][tx] = in[(size_t)(r0 + ty + i * 8) * 64 + s0 + tx];
  __syncthreads();
#pragma unroll
  for (int i = 0; i < 4; ++i)
    out[(size_t)(s0 + ty + i * 8) * 1024 + r0 + tx] = (__bf16)t[tx][ty + i * 8];
}

// ---------------- LayerNorm (C=1024) -> bf16 ----------------
__global__ __launch_bounds__(256) void ln_kernel(const float* __restrict__ x,
                                                 const float* __restrict__ g,
                                                 const float* __restrict__ b,
                                                 __bf16* __restrict__ out) {
  __shared__ float red[8];
  int row = blockIdx.x, tid = threadIdx.x;
  float4 v = ((const float4*)(x + (size_t)row * 1024))[tid];
  float s = v.x + v.y + v.z + v.w;
  float s2 = v.x * v.x + v.y * v.y + v.z * v.z + v.w * v.w;
#pragma unroll
  for (int m = 1; m < 64; m <<= 1) { s += __shfl_xor(s, m); s2 += __shfl_xor(s2, m); }
  if ((tid & 63) == 0) { red[tid >> 6] = s; red[4 + (tid >> 6)] = s2; }
  __syncthreads();
  s = red[0] + red[1] + red[2] + red[3];
  s2 = red[4] + red[5] + red[6] + red[7];
  float mu = s * (1.0f / 1024.0f);
  float var = s2 * (1.0f / 1024.0f) - mu * mu;
  float rs = rsqrtf(var + 1e-5f);
  float4 gg = ((const float4*)g)[tid];
  float4 bb = ((const float4*)b)[tid];
  bf16x4 o4;
  o4[0] = (__bf16)((v.x - mu) * rs * gg.x + bb.x);
  o4[1] = (__bf16)((v.y - mu) * rs * gg.y + bb.y);
  o4[2] = (__bf16)((v.z - mu) * rs * gg.z + bb.z);
  o4[3] = (__bf16)((v.w - mu) * rs * gg.w + bb.w);
  *(bf16x4*)(out + (size_t)row * 1024 + tid * 4) = o4;
}

// -------- FF2 reduce: out += p0 + p1 + b2  (f32 out, bf16 partials) --------
__global__ __launch_bounds__(256) void ff2_reduce(float* __restrict__ out,
                                                  const __bf16* __restrict__ p0,
                                                  const __bf16* __restrict__ p1,
                                                  const float* __restrict__ b2) {
  int i = blockIdx.x * 256 + threadIdx.x;  // float4 granule
  float4 v = ((const float4*)out)[i];
  bf16x4 a = ((const bf16x4*)p0)[i];
  bf16x4 b = ((const bf16x4*)p1)[i];
  float4 bb = ((const float4*)b2)[i & 255];
  v.x += (float)a[0] + (float)b[0] + bb.x;
  v.y += (float)a[1] + (float)b[1] + bb.y;
  v.z += (float)a[2] + (float)b[2] + bb.z;
  v.w += (float)a[3] + (float)b[3] + bb.w;
  ((float4*)out)[i] = v;
}

// ============ 8-phase 256x256 GEMM (FF2 only) ============
// EPI 5: bf16 partial store (split-K FF2): z==0 -> q_out, z==1 -> k_out
template <int EPI>
__global__ __launch_bounds__(512) void gemm8p(const __bf16* __restrict__ A,
                                              const __bf16* __restrict__ Bt,
                                              void* __restrict__ Cout,
                                              const float* __restrict__ bias,
                                              const float* __restrict__ resid,
                                              __bf16* __restrict__ q_out,
                                              __bf16* __restrict__ k_out,
                                              __bf16* __restrict__ vt_out,
                                              int M, int N, int K, int NBN) {
  __shared__ __align__(16) char lds[131072];
  const int tid = threadIdx.x;
  const int l = tid & 63, w = tid >> 6;
  const int wm = w >> 2, wn = w & 3;
  const int lr = l & 15, lg = l >> 4;

  int nwg = gridDim.x;
  int cpx = nwg >> 3;
  int orig = blockIdx.x;
  int wgid = (orig & 7) * cpx + (orig >> 3);
  int bn = wgid % NBN, bm = wgid / NBN;
  int n0 = bn * 256, m0 = bm * 256;

  const int Kloop = K / (int)gridDim.z;
  const int NT = Kloop >> 6;
  const size_t K2 = (size_t)K * 2;
  const size_t koff = (size_t)blockIdx.z * Kloop * 2;

  const int srow = tid >> 3, slot = tid & 7;
  const int sswz = (slot ^ (srow & 7)) << 4;
  const char* aA = (const char*)A + (size_t)(m0 + srow) * K2 + koff + sswz;
  const char* aB = (const char*)Bt + (size_t)(n0 + srow) * K2 + koff + sswz;

  auto stageA = [&](char* buf, int half, int kt) {
    char* d = buf + half * 16384 + tid * 16;
    const char* s = aA + (size_t)(half * 128) * K2 + (size_t)kt * 128;
    gload_lds16(s, d);
    gload_lds16(s + (size_t)64 * K2, d + 8192);
  };
  auto stageB = [&](char* buf, int half, int kt) {
    char* d = buf + 32768 + half * 16384 + tid * 16;
    const char* s = aB + (size_t)(half * 128) * K2 + (size_t)kt * 128;
    gload_lds16(s, d);
    gload_lds16(s + (size_t)64 * K2, d + 8192);
  };

  const int arow = (wm * 64 + lr) * 128;
  const int brow = (wn * 32 + lr) * 128;
  const int ck0 = ((lg) ^ (lr & 7)) << 4;
  const int ck1 = ((4 + lg) ^ (lr & 7)) << 4;

  f32x4 acc[8][4];
#pragma unroll
  for (int mi = 0; mi < 8; ++mi)
#pragma unroll
    for (int ni = 0; ni < 4; ++ni)
#pragma unroll
      for (int e = 0; e < 4; ++e) acc[mi][ni][e] = 0.0f;

  bf16x8 af[4][2], b0f[2][2], b1f[2][2];

  auto ldsA = [&](const char* buf, int mh) {
#pragma unroll
    for (int i = 0; i < 4; ++i) {
      const char* p = buf + mh * 16384 + arow + i * 2048;
      af[i][0] = *(const bf16x8*)(p + ck0);
      af[i][1] = *(const bf16x8*)(p + ck1);
    }
  };
  auto ldsB = [&](bf16x8 (&dst)[2][2], const char* buf, int nh) {
#pragma unroll
    for (int j = 0; j < 2; ++j) {
      const char* p = buf + 32768 + nh * 16384 + brow + j * 2048;
      dst[j][0] = *(const bf16x8*)(p + ck0);
      dst[j][1] = *(const bf16x8*)(p + ck1);
    }
  };
  auto mmq = [&](int mh, bf16x8 (&bf)[2][2], int nh) {
    __builtin_amdgcn_s_setprio(1);
#pragma unroll
    for (int i = 0; i < 4; ++i)
#pragma unroll
      for (int j = 0; j < 2; ++j) {
        int mi = mh * 4 + i, ni = nh * 2 + j;
        acc[mi][ni] = __builtin_amdgcn_mfma_f32_16x16x32_bf16(af[i][0], bf[j][0], acc[mi][ni], 0, 0, 0);
        acc[mi][ni] = __builtin_amdgcn_mfma_f32_16x16x32_bf16(af[i][1], bf[j][1], acc[mi][ni], 0, 0, 0);
      }
    __builtin_amdgcn_s_setprio(0);
  };

  char* bufE = lds;
  char* bufO = lds + 65536;

  stageA(bufE, 0, 0);
  stageB(bufE, 0, 0);
  stageB(bufE, 1, 0);
  stageA(bufE, 1, 0);
  if (NT > 1) { stageA(bufO, 0, 1); stageB(bufO, 0, 1); }
  else        { stageA(bufO, 0, 0); stageB(bufO, 0, 0); }
  vm4();
  bar();

  auto do_tile = [&](char* cur, char* oth, int t) {
    int kN = (t + 1 < NT) ? t + 1 : NT - 1;
    int kN2 = (t + 2 < NT) ? t + 2 : NT - 1;
    ldsA(cur, 0);
    ldsB(b0f, cur, 0);
    stageB(oth, 1, kN);
    bar(); lgkm0sb();
    mmq(0, b0f, 0);
    bar();
    ldsB(b1f, cur, 1);
    stageA(oth, 1, kN);
    vm6(); bar(); lgkm0sb();
    mmq(0, b1f, 1);
    bar();
    ldsA(cur, 1);
    stageA(cur, 0, kN2);
    bar(); lgkm0sb();
    mmq(1, b1f, 1);
    bar();
    stageB(cur, 0, kN2);
    vm6(); bar();
    mmq(1, b0f, 0);
    bar();
  };

  for (int t = 0; t < NT; t += 2) {
    do_tile(bufE, bufO, t);
    do_tile(bufO, bufE, t + 1);
  }

#pragma unroll
  for (int mi = 0; mi < 8; ++mi) {
    int rowb = m0 + (mi >> 2) * 128 + wm * 64 + (mi & 3) * 16 + lg * 4;
#pragma unroll
    for (int e = 0; e < 4; ++e) {
      int row = rowb + e;
#pragma unroll
      for (int ni = 0; ni < 4; ++ni) {
        int col = n0 + (ni >> 1) * 128 + wn * 32 + (ni & 1) * 16 + lr;
        float v = acc[mi][ni][e];
        size_t idx = (size_t)row * N + col;
        if (EPI == 0) {
          ((__bf16*)Cout)[idx] = (__bf16)v;
        } else if (EPI == 2) {
          v += bias[col];
          ((__bf16*)Cout)[idx] = (__bf16)fmaxf(v, 0.0f);
        } else if (EPI == 5) {
          (blockIdx.z ? k_out : q_out)[idx] = (__bf16)v;
        }
      }
    }
  }
}

// ============ 128x128 BK=32 GEMM, triple-buffer, 3 blocks/CU ============
// EPI 1: f32 out = resid + acc + bias   (proj)
// EPI 2: bf16 out = relu(acc + bias)    (FF1)
// EPI 4: QKV split-scatter: Qt [BH][64][T], Kh [BH][T][64], Vt [BH][64][T]
template <int EPI>
__global__ __launch_bounds__(256, 3) void gemm2p(const __bf16* __restrict__ A,
                                                 const __bf16* __restrict__ Bt,
                                                 void* __restrict__ Cout,
                                                 const float* __restrict__ bias,
                                                 const float* __restrict__ resid,
                                                 __bf16* __restrict__ q_out,
                                                 __bf16* __restrict__ k_out,
                                                 __bf16* __restrict__ vt_out,
                                                 int M, int N, int K, int NBN) {
  __shared__ __align__(16) char lds[49152];
  const int tid = threadIdx.x;
  const int l = tid & 63, w = tid >> 6;
  const int lr = l & 15, lg = l >> 4;

  int nwg = gridDim.x;
  int cpx = nwg >> 3;
  int orig = blockIdx.x;
  int wgid = (orig & 7) * cpx + (orig >> 3);
  int bn = wgid % NBN, bm = wgid / NBN;
  int n0 = bn * 128, m0 = bm * 128;

  const int Kloop = K / (int)gridDim.z;
  const int NT = Kloop >> 5;
  const size_t K2 = (size_t)K * 2;
  const size_t koff = (size_t)blockIdx.z * Kloop * 2;

  const int srow = tid >> 2;
  const int sslot = ((tid & 3) ^ ((tid >> 4) & 3)) << 4;
  const char* aA = (const char*)A + (size_t)(m0 + srow) * K2 + koff + sslot;
  const char* aB = (const char*)Bt + (size_t)(n0 + srow) * K2 + koff + sslot;

  auto stage = [&](int bufi, int kt) {
    char* d = lds + bufi * 16384 + tid * 16;
    const char* sA = aA + (size_t)kt * 64;
    const char* sB = aB + (size_t)kt * 64;
    gload_lds16(sA, d);
    gload_lds16(sA + (size_t)64 * K2, d + 4096);
    gload_lds16(sB, d + 8192);
    gload_lds16(sB + (size_t)64 * K2, d + 12288);
  };

  const int arow0 = ((w >> 1) * 64 + lr) * 64;
  const int brow0 = ((w & 1) * 64 + lr) * 64;
  const int cs = ((lg ^ (lr >> 2)) & 3) << 4;

  f32x4 acc[4][4];
#pragma unroll
  for (int mi = 0; mi < 4; ++mi)
#pragma unroll
    for (int ni = 0; ni < 4; ++ni)
#pragma unroll
      for (int e = 0; e < 4; ++e) acc[mi][ni][e] = 0.0f;

  stage(0, 0);
  stage(1, NT > 1 ? 1 : 0);
  vm4();
  bar();

  for (int t = 0; t < NT; ++t) {
    if (t + 2 < NT) stage((t + 2) % 3, t + 2);
    const char* buf = lds + (t % 3) * 16384;
    bf16x8 af[4], bfr[4];
#pragma unroll
    for (int i = 0; i < 4; ++i)
      af[i] = *(const bf16x8*)(buf + arow0 + i * 1024 + cs);
#pragma unroll
    for (int i = 0; i < 4; ++i)
      bfr[i] = *(const bf16x8*)(buf + 8192 + brow0 + i * 1024 + cs);
    lgkm0sb();
    __builtin_amdgcn_s_setprio(1);
#pragma unroll
    for (int mi = 0; mi < 4; ++mi)
#pragma unroll
      for (int ni = 0; ni < 4; ++ni)
        acc[mi][ni] = __builtin_amdgcn_mfma_f32_16x16x32_bf16(af[mi], bfr[ni], acc[mi][ni], 0, 0, 0);
    __builtin_amdgcn_s_setprio(0);
    if (t + 2 < NT) vm4(); else vm0();
    bar();
  }

#pragma unroll
  for (int mi = 0; mi < 4; ++mi) {
    int rowb = m0 + (w >> 1) * 64 + mi * 16 + lg * 4;
#pragma unroll
    for (int e = 0; e < 4; ++e) {
      int row = rowb + e;
#pragma unroll
      for (int ni = 0; ni < 4; ++ni) {
        int col = n0 + (w & 1) * 64 + ni * 16 + lr;
        float v = acc[mi][ni][e];
        size_t idx = (size_t)row * N + col;
        if (EPI == 1) {
          ((float*)Cout)[idx] = resid[idx] + v + bias[col];
        } else if (EPI == 2) {
          v += bias[col];
          ((__bf16*)Cout)[idx] = (__bf16)fmaxf(v, 0.0f);
        } else if (EPI == 0) {
          ((__bf16*)Cout)[idx] = (__bf16)v;
        } else {  // EPI 4: QKV scatter
          int b = row >> 11, t2 = row & 2047;
          int sel = col >> 10, cc = col & 1023, h = cc >> 6, d = cc & 63;
          int bh = b * 16 + h;
          __bf16 val = (__bf16)v;
          if (sel == 0)
            q_out[((size_t)bh * 64 + d) * 2048 + t2] = val;   // Q transposed
          else if (sel == 1)
            k_out[((size_t)bh * 2048 + t2) * 64 + d] = val;   // K row-major
          else
            vt_out[((size_t)bh * 64 + d) * 2048 + t2] = val;  // V transposed
        }
      }
    }
  }
}

// ---------------- causal flash attention v5 (LPT, 1 q-tile/block) -----------
// 4 waves/block, 32 q/wave (QBLK=128), KVBLK=64, dbuf K/V LDS, counted vmcnt.
// Grid (16, 64): block x handles q-tile t = 15-x (heaviest first -> LPT).
// Qt: [BH][64][2048]  Kh: [BH][2048][64]  Vt: [BH][64][2048]  o: [B][T][1024]
__global__ __launch_bounds__(256) void attn_kernel5(const __bf16* __restrict__ Qt,
                                                    const __bf16* __restrict__ Kh,
                                                    const __bf16* __restrict__ Vt,
                                                    __bf16* __restrict__ o) {
  __shared__ __align__(16) char Klds[16384];  // 2 x 64 keys x 128B, swizzled
  __shared__ __align__(16) char Vlds[16384];  // 2 x 64 dims x 128B, swizzled
  int tid = threadIdx.x;
  int l = tid & 63, w = tid >> 6;
  int lq = l & 31, hi = l >> 5;
  int bh = blockIdx.y;
  int b = bh >> 4, h = bh & 15;
  int t = 15 - (int)blockIdx.x;  // LPT: heavy tiles dispatched first

  const char* Kbase = (const char*)(Kh + (size_t)bh * 2048 * 64);
  const char* Vbase = (const char*)(Vt + (size_t)bh * 64 * 2048);
  const __bf16* Qbase = Qt + (size_t)bh * 64 * 2048;
  __bf16* Obase = o + (size_t)b * 2048 * 1024 + h * 64;

  int srow = tid >> 3;
  int schunk = (tid & 7) * 16;
  int sw0 = (srow & 7) << 4;
  int swz = (lq & 7) << 4;

  auto stageKV = [&](int bufi, int s0) {
    char* kd = Klds + bufi * 8192 + tid * 16;
    char* vd = Vlds + bufi * 8192 + tid * 16;
    gload_lds16(Kbase + (size_t)(s0 + srow) * 128 + (schunk ^ sw0), kd);
    gload_lds16(Kbase + (size_t)(s0 + srow + 32) * 128 + (schunk ^ sw0), kd + 4096);
    gload_lds16(Vbase + (size_t)srow * 4096 + s0 * 2 + (schunk ^ sw0), vd);
    gload_lds16(Vbase + (size_t)(srow + 32) * 4096 + s0 * 2 + (schunk ^ sw0), vd + 4096);
  };

  int qw = t * 128 + w * 32;
  int qglob = qw + lq;

  // Q B-fragments: qb[s][j] = Q[hs = s*16 + hi*8 + j][qw + lq]
  bf16x8 qb[4];
  const __bf16* qsrc = Qbase + (size_t)(hi * 8) * 2048 + qw + lq;
#pragma unroll
  for (int s = 0; s < 4; ++s)
#pragma unroll
    for (int j = 0; j < 8; ++j)
      qb[s][j] = qsrc[(size_t)(s * 16 + j) * 2048];

  f32x16 oacc0, oacc1;
#pragma unroll
  for (int i = 0; i < 16; ++i) { oacc0[i] = 0.0f; oacc1[i] = 0.0f; }
  float m_q = -3.0e38f, l_q = 0.0f;

  int nkb = 2 * t + 2;
  stageKV(0, 0);
  for (int kb = 0; kb < nkb; ++kb) {
    int s0 = kb * 64;
    if (kb + 1 < nkb) { stageKV((kb + 1) & 1, s0 + 64); vm4(); }
    else vm0();
    bar();
    const char* Kb = Klds + (kb & 1) * 8192;
    const char* Vb = Vlds + (kb & 1) * 8192;

    if (s0 <= qw + 31) {  // else: tile fully masked for this wave
      f32x16 st0, st1;
#pragma unroll
      for (int i = 0; i < 16; ++i) { st0[i] = 0.0f; st1[i] = 0.0f; }
#pragma unroll
      for (int s = 0; s < 4; ++s) {
        bf16x8 ka = *(const bf16x8*)(Kb + lq * 128 + ((s * 32 + hi * 16) ^ swz));
        st0 = __builtin_amdgcn_mfma_f32_32x32x16_bf16(ka, qb[s], st0, 0, 0, 0);
      }
#pragma unroll
      for (int s = 0; s < 4; ++s) {
        bf16x8 ka = *(const bf16x8*)(Kb + (32 + lq) * 128 + ((s * 32 + hi * 16) ^ swz));
        st1 = __builtin_amdgcn_mfma_f32_32x32x16_bf16(ka, qb[s], st1, 0, 0, 0);
      }
      if (s0 + 63 > qw) {  // diagonal tiles only
#pragma unroll
        for (int r = 0; r < 16; ++r) {
          int key0 = s0 + (r & 3) + 8 * (r >> 2) + 4 * hi;
          if (key0 > qglob) st0[r] = -1.0e38f;
          if (key0 + 32 > qglob) st1[r] = -1.0e38f;
        }
      }
      float mx8[8];
#pragma unroll
      for (int i = 0; i < 8; ++i)
        mx8[i] = fmaxf(fmaxf(st0[i], st0[i + 8]), fmaxf(st1[i], st1[i + 8]));
      float mx = fmaxf(fmaxf(fmaxf(mx8[0], mx8[1]), fmaxf(mx8[2], mx8[3])),
                       fmaxf(fmaxf(mx8[4], mx8[5]), fmaxf(mx8[6], mx8[7])));
      {
        float u = mx, v = mx;
        asm("v_permlane32_swap_b32 %0, %1" : "+v"(u), "+v"(v));
        mx = fmaxf(u, v);
      }
      float mt_s = mx * 0.03125f;
      if (__any(mt_s > m_q + 8.0f)) {
        float mnew = fmaxf(m_q, mt_s);
        float scv = exp2f((m_q - mnew) * 1.44269504f);
        m_q = mnew;
        l_q *= scv;
#pragma unroll
        for (int r = 0; r < 16; ++r) {
          int qr = (r & 3) + 8 * (r >> 2) + 4 * hi;
          float scO = __shfl(scv, qr);
          oacc0[r] *= scO;
          oacc1[r] *= scO;
        }
      }
      float m2 = m_q * 1.44269504f;
#pragma unroll
      for (int r = 0; r < 16; ++r) {
        st0[r] = exp2f(fmaf(st0[r], 0.045084389f, -m2));
        st1[r] = exp2f(fmaf(st1[r], 0.045084389f, -m2));
      }
      float s8[8];
#pragma unroll
      for (int i = 0; i < 8; ++i)
        s8[i] = (st0[i] + st0[i + 8]) + (st1[i] + st1[i + 8]);
      float ps = ((s8[0] + s8[1]) + (s8[2] + s8[3])) +
                 ((s8[4] + s8[5]) + (s8[6] + s8[7]));
      {
        float u = ps, v = ps;
        asm("v_permlane32_swap_b32 %0, %1" : "+v"(u), "+v"(v));
        ps = u + v;
      }
      l_q += ps;

      {
        unsigned int w0 = cvt_pk(st0[0], st0[1]), w1 = cvt_pk(st0[2], st0[3]);
        unsigned int w2 = cvt_pk(st0[4], st0[5]), w3 = cvt_pk(st0[6], st0[7]);
        asm("v_permlane32_swap_b32 %0, %1" : "+v"(w0), "+v"(w2));
        asm("v_permlane32_swap_b32 %0, %1" : "+v"(w1), "+v"(w3));
        bf16x8 pa0 = pack_frag(w0, w1, w2, w3);
        unsigned int w4 = cvt_pk(st0[8], st0[9]), w5 = cvt_pk(st0[10], st0[11]);
        unsigned int w6 = cvt_pk(st0[12], st0[13]), w7 = cvt_pk(st0[14], st0[15]);
        asm("v_permlane32_swap_b32 %0, %1" : "+v"(w4), "+v"(w6));
        asm("v_permlane32_swap_b32 %0, %1" : "+v"(w5), "+v"(w7));
        bf16x8 pa1 = pack_frag(w4, w5, w6, w7);
        bf16x8 v00 = *(const bf16x8*)(Vb + lq * 128 + ((hi * 16) ^ swz));
        bf16x8 v01 = *(const bf16x8*)(Vb + (32 + lq) * 128 + ((hi * 16) ^ swz));
        bf16x8 v10 = *(const bf16x8*)(Vb + lq * 128 + ((32 + hi * 16) ^ swz));
        bf16x8 v11 = *(const bf16x8*)(Vb + (32 + lq) * 128 + ((32 + hi * 16) ^ swz));
        oacc0 = __builtin_amdgcn_mfma_f32_32x32x16_bf16(pa0, v00, oacc0, 0, 0, 0);
        oacc1 = __builtin_amdgcn_mfma_f32_32x32x16_bf16(pa0, v01, oacc1, 0, 0, 0);
        oacc0 = __builtin_amdgcn_mfma_f32_32x32x16_bf16(pa1, v10, oacc0, 0, 0, 0);
        oacc1 = __builtin_amdgcn_mfma_f32_32x32x16_bf16(pa1, v11, oacc1, 0, 0, 0);
      }
      {
        unsigned int w0 = cvt_pk(st1[0], st1[1]), w1 = cvt_pk(st1[2], st1[3]);
        unsigned int w2 = cvt_pk(st1[4], st1[5]), w3 = cvt_pk(st1[6], st1[7]);
        asm("v_permlane32_swap_b32 %0, %1" : "+v"(w0), "+v"(w2));
        asm("v_permlane32_swap_b32 %0, %1" : "+v"(w1), "+v"(w3));
        bf16x8 pa0 = pack_frag(w0, w1, w2, w3);
        unsigned int w4 = cvt_pk(st1[8], st1[9]), w5 = cvt_pk(st1[10], st1[11]);
        unsigned int w6 = cvt_pk(st1[12], st1[13]), w7 = cvt_pk(st1[14], st1[15]);
        asm("v_permlane32_swap_b32 %0, %1" : "+v"(w4), "+v"(w6));
        asm("v_permlane32_swap_b32 %0, %1" : "+v"(w5), "+v"(w7));
        bf16x8 pa1 = pack_frag(w4, w5, w6, w7);
        bf16x8 v00 = *(const bf16x8*)(Vb + lq * 128 + ((64 + hi * 16) ^ swz));
        bf16x8 v01 = *(const bf16x8*)(Vb + (32 + lq) * 128 + ((64 + hi * 16) ^ swz));
        bf16x8 v10 = *(const bf16x8*)(Vb + lq * 128 + ((96 + hi * 16) ^ swz));
        bf16x8 v11 = *(const bf16x8*)(Vb + (32 + lq) * 128 + ((96 + hi * 16) ^ swz));
        oacc0 = __builtin_amdgcn_mfma_f32_32x32x16_bf16(pa0, v00, oacc0, 0, 0, 0);
        oacc1 = __builtin_amdgcn_mfma_f32_32x32x16_bf16(pa0, v01, oacc1, 0, 0, 0);
        oacc0 = __builtin_amdgcn_mfma_f32_32x32x16_bf16(pa1, v10, oacc0, 0, 0, 0);
        oacc1 = __builtin_amdgcn_mfma_f32_32x32x16_bf16(pa1, v11, oacc1, 0, 0, 0);
      }
    }
    bar();
  }
#pragma unroll
  for (int r = 0; r < 16; ++r) {
    int qr = (r & 3) + 8 * (r >> 2) + 4 * hi;
    float linv = 1.0f / __shfl(l_q, qr);
    size_t row = qw + qr;
    Obase[row * 1024 + lq] = (__bf16)(oacc0[r] * linv);
    Obase[row * 1024 + 32 + lq] = (__bf16)(oacc1[r] * linv);
  }
}

// ---------------- launcher ----------------
extern "C" void kernel_launch(void* const* d_in, const int* in_sizes, int n_in,
                              void* d_out, int out_size, void* d_ws, size_t ws_size,
                              hipStream_t stream) {
  const float* x     = (const float*)d_in[0];
  const float* Wq    = (const float*)d_in[1];
  const float* Wk    = (const float*)d_in[2];
  const float* Wv    = (const float*)d_in[3];
  const float* Wproj = (const float*)d_in[4];
  const float* bproj = (const float*)d_in[5];
  const float* ln1_g = (const float*)d_in[6];
  const float* ln1_b = (const float*)d_in[7];
  const float* ln2_g = (const float*)d_in[8];
  const float* ln2_b = (const float*)d_in[9];
  const float* W1    = (const float*)d_in[10];
  const float* b1    = (const float*)d_in[11];
  const float* W2    = (const float*)d_in[12];
  const float* b2    = (const float*)d_in[13];
  float* out = (float*)d_out;

  char* ws = (char*)d_ws;
  __bf16* actA   = (__bf16*)(ws + 0);          // 16 MB (ln1 out, then ln2 out)
  __bf16* WqkvT  = (__bf16*)(ws + 16777216);   // 6 MB
  __bf16* WprojT = (__bf16*)(ws + 23068672);   // 2 MB
  __bf16* W1T    = (__bf16*)(ws + 25165824);   // 8 MB
  __bf16* W2T    = (__bf16*)(ws + 33554432);   // 8 MB
  __bf16* Qt     = (__bf16*)(ws + 41943040);   // 16 MB [BH][64][2048]
  __bf16* Kh     = (__bf16*)(ws + 58720256);   // 16 MB [BH][2048][64]
  __bf16* Vt     = (__bf16*)(ws + 75497472);   // 16 MB [BH][64][2048]
  __bf16* obuf   = (__bf16*)(ws + 92274688);   // 16 MB
  __bf16* ff1    = Qt;                         // 64 MB (Qt..obuf dead by then)
  __bf16* p0     = (__bf16*)(ws + 0);          // 16 MB (actA dead after FF1)
  __bf16* p1     = (__bf16*)(ws + 16777216);   // 16 MB (weights dead by FF2)

  dim3 t32x8(32, 8);
  qkv_repack<<<dim3(2, 32, 48), t32x8, 0, stream>>>(Wq, Wk, Wv, WqkvT);
  transpose_cvt<<<dim3(32, 32), t32x8, 0, stream>>>(Wproj, WprojT, 1024, 1024);
  transpose_cvt<<<dim3(128, 32), t32x8, 0, stream>>>(W1, W1T, 1024, 4096);
  transpose_cvt<<<dim3(32, 128), t32x8, 0, stream>>>(W2, W2T, 4096, 1024);

  ln_kernel<<<8192, 256, 0, stream>>>(x, ln1_g, ln1_b, actA);
  gemm2p<4><<<dim3(1536, 1, 1), 256, 0, stream>>>(actA, WqkvT, nullptr, nullptr, nullptr,
                                                  Qt, Kh, Vt, 8192, 3072, 1024, 24);
  attn_kernel5<<<dim3(16, 64), 256, 0, stream>>>(Qt, Kh, Vt, obuf);
  gemm2p<1><<<dim3(512, 1, 1), 256, 0, stream>>>(obuf, WprojT, out, bproj, x,
                                                 nullptr, nullptr, nullptr, 8192, 1024, 1024, 8);
  ln_kernel<<<8192, 256, 0, stream>>>(out, ln2_g, ln2_b, actA);
  gemm2p<2><<<dim3(2048, 1, 1), 256, 0, stream>>>(actA, W1T, ff1, b1, nullptr,
                                                  nullptr, nullptr, nullptr, 8192, 4096, 1024, 32);
  gemm8p<5><<<dim3(128, 1, 2), 512, 0, stream>>>(ff1, W2T, nullptr, nullptr, nullptr,
                                                 p0, p1, nullptr, 8192, 1024, 4096, 4);
  ff2_reduce<<<8192, 256, 0, stream>>>(out, p0, p1, b2);
}

// Round 20
// 382.795 us; speedup vs baseline: 1.2091x; 1.2091x over previous
//
#include <hip/hip_runtime.h>
#include <hip/hip_bf16.h>
#include <stdint.h>

typedef __attribute__((ext_vector_type(8))) __bf16 bf16x8;
typedef __attribute__((ext_vector_type(4))) __bf16 bf16x4;
typedef __attribute__((ext_vector_type(4))) float f32x4;
typedef __attribute__((ext_vector_type(16))) float f32x16;
typedef __attribute__((ext_vector_type(4))) unsigned int u32x4;

typedef const __attribute__((address_space(1))) void* gas_ptr;
typedef __attribute__((address_space(3))) void* las_ptr;

static __device__ __forceinline__ void gload_lds16(const void* g, void* l) {
  __builtin_amdgcn_global_load_lds((gas_ptr)g, (las_ptr)l, 16, 0, 0);
}

static __device__ __forceinline__ unsigned int cvt_pk(float lo, float hi) {
  unsigned int r;
  asm("v_cvt_pk_bf16_f32 %0, %1, %2" : "=v"(r) : "v"(lo), "v"(hi));
  return r;
}

static __device__ __forceinline__ bf16x8 pack_frag(unsigned int a, unsigned int b,
                                                   unsigned int c, unsigned int d) {
  u32x4 t = {a, b, c, d};
  return __builtin_bit_cast(bf16x8, t);
}

static __device__ __forceinline__ void vm4() {
  asm volatile("s_waitcnt vmcnt(4)" ::: "memory");
}
static __device__ __forceinline__ void vm6() {
  asm volatile("s_waitcnt vmcnt(6)" ::: "memory");
}
static __device__ __forceinline__ void vm0() {
  asm volatile("s_waitcnt vmcnt(0)" ::: "memory");
}
static __device__ __forceinline__ void lgkm0sb() {
  asm volatile("s_waitcnt lgkmcnt(0)" ::: "memory");
  __builtin_amdgcn_sched_barrier(0);
}
static __device__ __forceinline__ void bar() {
  asm volatile("" ::: "memory");
  __builtin_amdgcn_s_barrier();
  asm volatile("" ::: "memory");
}

// ---------------- generic transpose + fp32->bf16 ----------------
__global__ void transpose_cvt(const float* __restrict__ in, __bf16* __restrict__ out,
                              int R, int S) {
  __shared__ float t[32][33];
  int tx = threadIdx.x, ty = threadIdx.y;
  int r0 = blockIdx.y * 32, s0 = blockIdx.x * 32;
#pragma unroll
  for (int i = 0; i < 4; ++i) {
    int r = r0 + ty + i * 8;
    if (r < R && (s0 + tx) < S) t[ty + i * 8][tx] = in[(size_t)r * S + s0 + tx];
  }
  __syncthreads();
#pragma unroll
  for (int i = 0; i < 4; ++i) {
    int s = s0 + ty + i * 8;
    if (s < S && (r0 + tx) < R) out[(size_t)s * R + r0 + tx] = (__bf16)t[tx][ty + i * 8];
  }
}

// Wq/Wk/Wv [H=16][C=1024][HS=64] -> WqkvT bf16 [3*1024 rows][1024 cols]
__global__ void qkv_repack(const float* __restrict__ Wq, const float* __restrict__ Wk,
                           const float* __restrict__ Wv, __bf16* __restrict__ outT) {
  __shared__ float t[32][33];
  int z = blockIdx.z, sel = z >> 4, h = z & 15;
  const float* in = (sel == 0 ? Wq : sel == 1 ? Wk : Wv) + (size_t)h * 1024 * 64;
  __bf16* out = outT + (size_t)(sel * 1024 + h * 64) * 1024;
  int tx = threadIdx.x, ty = threadIdx.y;
  int r0 = blockIdx.y * 32, s0 = blockIdx.x * 32;
#pragma unroll
  for (int i = 0; i < 4; ++i)
    t[ty + i * 8][tx] = in[(size_t)(r0 + ty + i * 8) * 64 + s0 + tx];
  __syncthreads();
#pragma unroll
  for (int i = 0; i < 4; ++i)
    out[(size_t)(s0 + ty + i * 8) * 1024 + r0 + tx] = (__bf16)t[tx][ty + i * 8];
}

// ---------------- LayerNorm (C=1024) -> bf16 ----------------
__global__ __launch_bounds__(256) void ln_kernel(const float* __restrict__ x,
                                                 const float* __restrict__ g,
                                                 const float* __restrict__ b,
                                                 __bf16* __restrict__ out) {
  __shared__ float red[8];
  int row = blockIdx.x, tid = threadIdx.x;
  float4 v = ((const float4*)(x + (size_t)row * 1024))[tid];
  float s = v.x + v.y + v.z + v.w;
  float s2 = v.x * v.x + v.y * v.y + v.z * v.z + v.w * v.w;
#pragma unroll
  for (int m = 1; m < 64; m <<= 1) { s += __shfl_xor(s, m); s2 += __shfl_xor(s2, m); }
  if ((tid & 63) == 0) { red[tid >> 6] = s; red[4 + (tid >> 6)] = s2; }
  __syncthreads();
  s = red[0] + red[1] + red[2] + red[3];
  s2 = red[4] + red[5] + red[6] + red[7];
  float mu = s * (1.0f / 1024.0f);
  float var = s2 * (1.0f / 1024.0f) - mu * mu;
  float rs = rsqrtf(var + 1e-5f);
  float4 gg = ((const float4*)g)[tid];
  float4 bb = ((const float4*)b)[tid];
  bf16x4 o4;
  o4[0] = (__bf16)((v.x - mu) * rs * gg.x + bb.x);
  o4[1] = (__bf16)((v.y - mu) * rs * gg.y + bb.y);
  o4[2] = (__bf16)((v.z - mu) * rs * gg.z + bb.z);
  o4[3] = (__bf16)((v.w - mu) * rs * gg.w + bb.w);
  *(bf16x4*)(out + (size_t)row * 1024 + tid * 4) = o4;
}

// -------- FF2 reduce: out += p0 + p1 + b2  (f32 out, bf16 partials) --------
__global__ __launch_bounds__(256) void ff2_reduce(float* __restrict__ out,
                                                  const __bf16* __restrict__ p0,
                                                  const __bf16* __restrict__ p1,
                                                  const float* __restrict__ b2) {
  int i = blockIdx.x * 256 + threadIdx.x;  // float4 granule
  float4 v = ((const float4*)out)[i];
  bf16x4 a = ((const bf16x4*)p0)[i];
  bf16x4 b = ((const bf16x4*)p1)[i];
  float4 bb = ((const float4*)b2)[i & 255];
  v.x += (float)a[0] + (float)b[0] + bb.x;
  v.y += (float)a[1] + (float)b[1] + bb.y;
  v.z += (float)a[2] + (float)b[2] + bb.z;
  v.w += (float)a[3] + (float)b[3] + bb.w;
  ((float4*)out)[i] = v;
}

// ============ 8-phase 256x256 GEMM (FF1, FF2) ============
// EPI 2: bf16 out = relu(acc + bias)    (FF1)
// EPI 5: bf16 partial store (split-K FF2): z==0 -> q_out, z==1 -> k_out
template <int EPI>
__global__ __launch_bounds__(512) void gemm8p(const __bf16* __restrict__ A,
                                              const __bf16* __restrict__ Bt,
                                              void* __restrict__ Cout,
                                              const float* __restrict__ bias,
                                              const float* __restrict__ resid,
                                              __bf16* __restrict__ q_out,
                                              __bf16* __restrict__ k_out,
                                              __bf16* __restrict__ vt_out,
                                              int M, int N, int K, int NBN) {
  __shared__ __align__(16) char lds[131072];
  const int tid = threadIdx.x;
  const int l = tid & 63, w = tid >> 6;
  const int wm = w >> 2, wn = w & 3;
  const int lr = l & 15, lg = l >> 4;

  int nwg = gridDim.x;
  int cpx = nwg >> 3;
  int orig = blockIdx.x;
  int wgid = (orig & 7) * cpx + (orig >> 3);
  int bn = wgid % NBN, bm = wgid / NBN;
  int n0 = bn * 256, m0 = bm * 256;

  const int Kloop = K / (int)gridDim.z;
  const int NT = Kloop >> 6;
  const size_t K2 = (size_t)K * 2;
  const size_t koff = (size_t)blockIdx.z * Kloop * 2;

  const int srow = tid >> 3, slot = tid & 7;
  const int sswz = (slot ^ (srow & 7)) << 4;
  const char* aA = (const char*)A + (size_t)(m0 + srow) * K2 + koff + sswz;
  const char* aB = (const char*)Bt + (size_t)(n0 + srow) * K2 + koff + sswz;

  auto stageA = [&](char* buf, int half, int kt) {
    char* d = buf + half * 16384 + tid * 16;
    const char* s = aA + (size_t)(half * 128) * K2 + (size_t)kt * 128;
    gload_lds16(s, d);
    gload_lds16(s + (size_t)64 * K2, d + 8192);
  };
  auto stageB = [&](char* buf, int half, int kt) {
    char* d = buf + 32768 + half * 16384 + tid * 16;
    const char* s = aB + (size_t)(half * 128) * K2 + (size_t)kt * 128;
    gload_lds16(s, d);
    gload_lds16(s + (size_t)64 * K2, d + 8192);
  };

  const int arow = (wm * 64 + lr) * 128;
  const int brow = (wn * 32 + lr) * 128;
  const int ck0 = ((lg) ^ (lr & 7)) << 4;
  const int ck1 = ((4 + lg) ^ (lr & 7)) << 4;

  f32x4 acc[8][4];
#pragma unroll
  for (int mi = 0; mi < 8; ++mi)
#pragma unroll
    for (int ni = 0; ni < 4; ++ni)
#pragma unroll
      for (int e = 0; e < 4; ++e) acc[mi][ni][e] = 0.0f;

  bf16x8 af[4][2], b0f[2][2], b1f[2][2];

  auto ldsA = [&](const char* buf, int mh) {
#pragma unroll
    for (int i = 0; i < 4; ++i) {
      const char* p = buf + mh * 16384 + arow + i * 2048;
      af[i][0] = *(const bf16x8*)(p + ck0);
      af[i][1] = *(const bf16x8*)(p + ck1);
    }
  };
  auto ldsB = [&](bf16x8 (&dst)[2][2], const char* buf, int nh) {
#pragma unroll
    for (int j = 0; j < 2; ++j) {
      const char* p = buf + 32768 + nh * 16384 + brow + j * 2048;
      dst[j][0] = *(const bf16x8*)(p + ck0);
      dst[j][1] = *(const bf16x8*)(p + ck1);
    }
  };
  auto mmq = [&](int mh, bf16x8 (&bf)[2][2], int nh) {
    __builtin_amdgcn_s_setprio(1);
#pragma unroll
    for (int i = 0; i < 4; ++i)
#pragma unroll
      for (int j = 0; j < 2; ++j) {
        int mi = mh * 4 + i, ni = nh * 2 + j;
        acc[mi][ni] = __builtin_amdgcn_mfma_f32_16x16x32_bf16(af[i][0], bf[j][0], acc[mi][ni], 0, 0, 0);
        acc[mi][ni] = __builtin_amdgcn_mfma_f32_16x16x32_bf16(af[i][1], bf[j][1], acc[mi][ni], 0, 0, 0);
      }
    __builtin_amdgcn_s_setprio(0);
  };

  char* bufE = lds;
  char* bufO = lds + 65536;

  stageA(bufE, 0, 0);
  stageB(bufE, 0, 0);
  stageB(bufE, 1, 0);
  stageA(bufE, 1, 0);
  if (NT > 1) { stageA(bufO, 0, 1); stageB(bufO, 0, 1); }
  else        { stageA(bufO, 0, 0); stageB(bufO, 0, 0); }
  vm4();
  bar();

  auto do_tile = [&](char* cur, char* oth, int t) {
    int kN = (t + 1 < NT) ? t + 1 : NT - 1;
    int kN2 = (t + 2 < NT) ? t + 2 : NT - 1;
    ldsA(cur, 0);
    ldsB(b0f, cur, 0);
    stageB(oth, 1, kN);
    bar(); lgkm0sb();
    mmq(0, b0f, 0);
    bar();
    ldsB(b1f, cur, 1);
    stageA(oth, 1, kN);
    vm6(); bar(); lgkm0sb();
    mmq(0, b1f, 1);
    bar();
    ldsA(cur, 1);
    stageA(cur, 0, kN2);
    bar(); lgkm0sb();
    mmq(1, b1f, 1);
    bar();
    stageB(cur, 0, kN2);
    vm6(); bar();
    mmq(1, b0f, 0);
    bar();
  };

  for (int t = 0; t < NT; t += 2) {
    do_tile(bufE, bufO, t);
    do_tile(bufO, bufE, t + 1);
  }

#pragma unroll
  for (int mi = 0; mi < 8; ++mi) {
    int rowb = m0 + (mi >> 2) * 128 + wm * 64 + (mi & 3) * 16 + lg * 4;
#pragma unroll
    for (int e = 0; e < 4; ++e) {
      int row = rowb + e;
#pragma unroll
      for (int ni = 0; ni < 4; ++ni) {
        int col = n0 + (ni >> 1) * 128 + wn * 32 + (ni & 1) * 16 + lr;
        float v = acc[mi][ni][e];
        size_t idx = (size_t)row * N + col;
        if (EPI == 0) {
          ((__bf16*)Cout)[idx] = (__bf16)v;
        } else if (EPI == 2) {
          v += bias[col];
          ((__bf16*)Cout)[idx] = (__bf16)fmaxf(v, 0.0f);
        } else if (EPI == 5) {
          (blockIdx.z ? k_out : q_out)[idx] = (__bf16)v;
        }
      }
    }
  }
}

// ============ 128x128 BK=32 GEMM, triple-buffer, 3 blocks/CU ============
// EPI 1: f32 out = resid + acc + bias   (proj)
// EPI 4: QKV split-scatter: Qt [BH][64][T], Kh [BH][T][64], Vt [BH][64][T]
template <int EPI>
__global__ __launch_bounds__(256, 3) void gemm2p(const __bf16* __restrict__ A,
                                                 const __bf16* __restrict__ Bt,
                                                 void* __restrict__ Cout,
                                                 const float* __restrict__ bias,
                                                 const float* __restrict__ resid,
                                                 __bf16* __restrict__ q_out,
                                                 __bf16* __restrict__ k_out,
                                                 __bf16* __restrict__ vt_out,
                                                 int M, int N, int K, int NBN) {
  __shared__ __align__(16) char lds[49152];
  const int tid = threadIdx.x;
  const int l = tid & 63, w = tid >> 6;
  const int lr = l & 15, lg = l >> 4;

  int nwg = gridDim.x;
  int cpx = nwg >> 3;
  int orig = blockIdx.x;
  int wgid = (orig & 7) * cpx + (orig >> 3);
  int bn = wgid % NBN, bm = wgid / NBN;
  int n0 = bn * 128, m0 = bm * 128;

  const int Kloop = K / (int)gridDim.z;
  const int NT = Kloop >> 5;
  const size_t K2 = (size_t)K * 2;
  const size_t koff = (size_t)blockIdx.z * Kloop * 2;

  const int srow = tid >> 2;
  const int sslot = ((tid & 3) ^ ((tid >> 4) & 3)) << 4;
  const char* aA = (const char*)A + (size_t)(m0 + srow) * K2 + koff + sslot;
  const char* aB = (const char*)Bt + (size_t)(n0 + srow) * K2 + koff + sslot;

  auto stage = [&](int bufi, int kt) {
    char* d = lds + bufi * 16384 + tid * 16;
    const char* sA = aA + (size_t)kt * 64;
    const char* sB = aB + (size_t)kt * 64;
    gload_lds16(sA, d);
    gload_lds16(sA + (size_t)64 * K2, d + 4096);
    gload_lds16(sB, d + 8192);
    gload_lds16(sB + (size_t)64 * K2, d + 12288);
  };

  const int arow0 = ((w >> 1) * 64 + lr) * 64;
  const int brow0 = ((w & 1) * 64 + lr) * 64;
  const int cs = ((lg ^ (lr >> 2)) & 3) << 4;

  f32x4 acc[4][4];
#pragma unroll
  for (int mi = 0; mi < 4; ++mi)
#pragma unroll
    for (int ni = 0; ni < 4; ++ni)
#pragma unroll
      for (int e = 0; e < 4; ++e) acc[mi][ni][e] = 0.0f;

  stage(0, 0);
  stage(1, NT > 1 ? 1 : 0);
  vm4();
  bar();

  for (int t = 0; t < NT; ++t) {
    if (t + 2 < NT) stage((t + 2) % 3, t + 2);
    const char* buf = lds + (t % 3) * 16384;
    bf16x8 af[4], bfr[4];
#pragma unroll
    for (int i = 0; i < 4; ++i)
      af[i] = *(const bf16x8*)(buf + arow0 + i * 1024 + cs);
#pragma unroll
    for (int i = 0; i < 4; ++i)
      bfr[i] = *(const bf16x8*)(buf + 8192 + brow0 + i * 1024 + cs);
    lgkm0sb();
    __builtin_amdgcn_s_setprio(1);
#pragma unroll
    for (int mi = 0; mi < 4; ++mi)
#pragma unroll
      for (int ni = 0; ni < 4; ++ni)
        acc[mi][ni] = __builtin_amdgcn_mfma_f32_16x16x32_bf16(af[mi], bfr[ni], acc[mi][ni], 0, 0, 0);
    __builtin_amdgcn_s_setprio(0);
    if (t + 2 < NT) vm4(); else vm0();
    bar();
  }

#pragma unroll
  for (int mi = 0; mi < 4; ++mi) {
    int rowb = m0 + (w >> 1) * 64 + mi * 16 + lg * 4;
#pragma unroll
    for (int e = 0; e < 4; ++e) {
      int row = rowb + e;
#pragma unroll
      for (int ni = 0; ni < 4; ++ni) {
        int col = n0 + (w & 1) * 64 + ni * 16 + lr;
        float v = acc[mi][ni][e];
        size_t idx = (size_t)row * N + col;
        if (EPI == 1) {
          ((float*)Cout)[idx] = resid[idx] + v + bias[col];
        } else if (EPI == 0) {
          ((__bf16*)Cout)[idx] = (__bf16)v;
        } else {  // EPI 4: QKV scatter
          int b = row >> 11, t2 = row & 2047;
          int sel = col >> 10, cc = col & 1023, h = cc >> 6, d = cc & 63;
          int bh = b * 16 + h;
          __bf16 val = (__bf16)v;
          if (sel == 0)
            q_out[((size_t)bh * 64 + d) * 2048 + t2] = val;   // Q transposed
          else if (sel == 1)
            k_out[((size_t)bh * 2048 + t2) * 64 + d] = val;   // K row-major
          else
            vt_out[((size_t)bh * 64 + d) * 2048 + t2] = val;  // V transposed
        }
      }
    }
  }
}

// ---------------- causal flash attention v4 (dbuf staging) ------------------
// 4 waves/block, 32 q/wave (QBLK=128), KVBLK=64, double-buffered K/V LDS with
// counted vmcnt. Block handles q-tile pair (p, 15-p) -> uniform 34 kv-tiles.
// Qt: [BH][64][2048]  Kh: [BH][2048][64]  Vt: [BH][64][2048]  o: [B][T][1024]
__global__ __launch_bounds__(256) void attn_kernel4(const __bf16* __restrict__ Qt,
                                                    const __bf16* __restrict__ Kh,
                                                    const __bf16* __restrict__ Vt,
                                                    __bf16* __restrict__ o) {
  __shared__ __align__(16) char Klds[16384];  // 2 x 64 keys x 128B, swizzled
  __shared__ __align__(16) char Vlds[16384];  // 2 x 64 dims x 128B, swizzled
  int tid = threadIdx.x;
  int l = tid & 63, w = tid >> 6;
  int lq = l & 31, hi = l >> 5;
  int p = blockIdx.x, bh = blockIdx.y;
  int b = bh >> 4, h = bh & 15;

  const char* Kbase = (const char*)(Kh + (size_t)bh * 2048 * 64);
  const char* Vbase = (const char*)(Vt + (size_t)bh * 64 * 2048);
  const __bf16* Qbase = Qt + (size_t)bh * 64 * 2048;
  __bf16* Obase = o + (size_t)b * 2048 * 1024 + h * 64;

  int srow = tid >> 3;
  int schunk = (tid & 7) * 16;
  int sw0 = (srow & 7) << 4;
  int swz = (lq & 7) << 4;

  auto stageKV = [&](int bufi, int s0) {
    char* kd = Klds + bufi * 8192 + tid * 16;
    char* vd = Vlds + bufi * 8192 + tid * 16;
    gload_lds16(Kbase + (size_t)(s0 + srow) * 128 + (schunk ^ sw0), kd);
    gload_lds16(Kbase + (size_t)(s0 + srow + 32) * 128 + (schunk ^ sw0), kd + 4096);
    gload_lds16(Vbase + (size_t)srow * 4096 + s0 * 2 + (schunk ^ sw0), vd);
    gload_lds16(Vbase + (size_t)(srow + 32) * 4096 + s0 * 2 + (schunk ^ sw0), vd + 4096);
  };

  for (int sweep = 0; sweep < 2; ++sweep) {
    int t = (sweep == 0) ? p : 15 - p;
    int qw = t * 128 + w * 32;
    int qglob = qw + lq;

    // Q B-fragments: qb[s][j] = Q[hs = s*16 + hi*8 + j][qw + lq]
    bf16x8 qb[4];
    const __bf16* qsrc = Qbase + (size_t)(hi * 8) * 2048 + qw + lq;
#pragma unroll
    for (int s = 0; s < 4; ++s)
#pragma unroll
      for (int j = 0; j < 8; ++j)
        qb[s][j] = qsrc[(size_t)(s * 16 + j) * 2048];

    f32x16 oacc0, oacc1;
#pragma unroll
    for (int i = 0; i < 16; ++i) { oacc0[i] = 0.0f; oacc1[i] = 0.0f; }
    float m_q = -3.0e38f, l_q = 0.0f;

    int nkb = 2 * t + 2;
    stageKV(0, 0);
    for (int kb = 0; kb < nkb; ++kb) {
      int s0 = kb * 64;
      if (kb + 1 < nkb) { stageKV((kb + 1) & 1, s0 + 64); vm4(); }
      else vm0();
      bar();
      const char* Kb = Klds + (kb & 1) * 8192;
      const char* Vb = Vlds + (kb & 1) * 8192;

      if (s0 <= qw + 31) {  // else: tile fully masked for this wave
        f32x16 st0, st1;
#pragma unroll
        for (int i = 0; i < 16; ++i) { st0[i] = 0.0f; st1[i] = 0.0f; }
#pragma unroll
        for (int s = 0; s < 4; ++s) {
          bf16x8 ka = *(const bf16x8*)(Kb + lq * 128 + ((s * 32 + hi * 16) ^ swz));
          st0 = __builtin_amdgcn_mfma_f32_32x32x16_bf16(ka, qb[s], st0, 0, 0, 0);
        }
#pragma unroll
        for (int s = 0; s < 4; ++s) {
          bf16x8 ka = *(const bf16x8*)(Kb + (32 + lq) * 128 + ((s * 32 + hi * 16) ^ swz));
          st1 = __builtin_amdgcn_mfma_f32_32x32x16_bf16(ka, qb[s], st1, 0, 0, 0);
        }
        if (s0 + 63 > qw) {  // diagonal tiles only
#pragma unroll
          for (int r = 0; r < 16; ++r) {
            int key0 = s0 + (r & 3) + 8 * (r >> 2) + 4 * hi;
            if (key0 > qglob) st0[r] = -1.0e38f;
            if (key0 + 32 > qglob) st1[r] = -1.0e38f;
          }
        }
        float mx8[8];
#pragma unroll
        for (int i = 0; i < 8; ++i)
          mx8[i] = fmaxf(fmaxf(st0[i], st0[i + 8]), fmaxf(st1[i], st1[i + 8]));
        float mx = fmaxf(fmaxf(fmaxf(mx8[0], mx8[1]), fmaxf(mx8[2], mx8[3])),
                         fmaxf(fmaxf(mx8[4], mx8[5]), fmaxf(mx8[6], mx8[7])));
        {
          float u = mx, v = mx;
          asm("v_permlane32_swap_b32 %0, %1" : "+v"(u), "+v"(v));
          mx = fmaxf(u, v);
        }
        float mt_s = mx * 0.03125f;
        if (__any(mt_s > m_q + 8.0f)) {
          float mnew = fmaxf(m_q, mt_s);
          float scv = exp2f((m_q - mnew) * 1.44269504f);
          m_q = mnew;
          l_q *= scv;
#pragma unroll
          for (int r = 0; r < 16; ++r) {
            int qr = (r & 3) + 8 * (r >> 2) + 4 * hi;
            float scO = __shfl(scv, qr);
            oacc0[r] *= scO;
            oacc1[r] *= scO;
          }
        }
        float m2 = m_q * 1.44269504f;
#pragma unroll
        for (int r = 0; r < 16; ++r) {
          st0[r] = exp2f(fmaf(st0[r], 0.045084389f, -m2));
          st1[r] = exp2f(fmaf(st1[r], 0.045084389f, -m2));
        }
        float s8[8];
#pragma unroll
        for (int i = 0; i < 8; ++i)
          s8[i] = (st0[i] + st0[i + 8]) + (st1[i] + st1[i + 8]);
        float ps = ((s8[0] + s8[1]) + (s8[2] + s8[3])) +
                   ((s8[4] + s8[5]) + (s8[6] + s8[7]));
        {
          float u = ps, v = ps;
          asm("v_permlane32_swap_b32 %0, %1" : "+v"(u), "+v"(v));
          ps = u + v;
        }
        l_q += ps;

        {
          unsigned int w0 = cvt_pk(st0[0], st0[1]), w1 = cvt_pk(st0[2], st0[3]);
          unsigned int w2 = cvt_pk(st0[4], st0[5]), w3 = cvt_pk(st0[6], st0[7]);
          asm("v_permlane32_swap_b32 %0, %1" : "+v"(w0), "+v"(w2));
          asm("v_permlane32_swap_b32 %0, %1" : "+v"(w1), "+v"(w3));
          bf16x8 pa0 = pack_frag(w0, w1, w2, w3);
          unsigned int w4 = cvt_pk(st0[8], st0[9]), w5 = cvt_pk(st0[10], st0[11]);
          unsigned int w6 = cvt_pk(st0[12], st0[13]), w7 = cvt_pk(st0[14], st0[15]);
          asm("v_permlane32_swap_b32 %0, %1" : "+v"(w4), "+v"(w6));
          asm("v_permlane32_swap_b32 %0, %1" : "+v"(w5), "+v"(w7));
          bf16x8 pa1 = pack_frag(w4, w5, w6, w7);
          bf16x8 v00 = *(const bf16x8*)(Vb + lq * 128 + ((hi * 16) ^ swz));
          bf16x8 v01 = *(const bf16x8*)(Vb + (32 + lq) * 128 + ((hi * 16) ^ swz));
          bf16x8 v10 = *(const bf16x8*)(Vb + lq * 128 + ((32 + hi * 16) ^ swz));
          bf16x8 v11 = *(const bf16x8*)(Vb + (32 + lq) * 128 + ((32 + hi * 16) ^ swz));
          oacc0 = __builtin_amdgcn_mfma_f32_32x32x16_bf16(pa0, v00, oacc0, 0, 0, 0);
          oacc1 = __builtin_amdgcn_mfma_f32_32x32x16_bf16(pa0, v01, oacc1, 0, 0, 0);
          oacc0 = __builtin_amdgcn_mfma_f32_32x32x16_bf16(pa1, v10, oacc0, 0, 0, 0);
          oacc1 = __builtin_amdgcn_mfma_f32_32x32x16_bf16(pa1, v11, oacc1, 0, 0, 0);
        }
        {
          unsigned int w0 = cvt_pk(st1[0], st1[1]), w1 = cvt_pk(st1[2], st1[3]);
          unsigned int w2 = cvt_pk(st1[4], st1[5]), w3 = cvt_pk(st1[6], st1[7]);
          asm("v_permlane32_swap_b32 %0, %1" : "+v"(w0), "+v"(w2));
          asm("v_permlane32_swap_b32 %0, %1" : "+v"(w1), "+v"(w3));
          bf16x8 pa0 = pack_frag(w0, w1, w2, w3);
          unsigned int w4 = cvt_pk(st1[8], st1[9]), w5 = cvt_pk(st1[10], st1[11]);
          unsigned int w6 = cvt_pk(st1[12], st1[13]), w7 = cvt_pk(st1[14], st1[15]);
          asm("v_permlane32_swap_b32 %0, %1" : "+v"(w4), "+v"(w6));
          asm("v_permlane32_swap_b32 %0, %1" : "+v"(w5), "+v"(w7));
          bf16x8 pa1 = pack_frag(w4, w5, w6, w7);
          bf16x8 v00 = *(const bf16x8*)(Vb + lq * 128 + ((64 + hi * 16) ^ swz));
          bf16x8 v01 = *(const bf16x8*)(Vb + (32 + lq) * 128 + ((64 + hi * 16) ^ swz));
          bf16x8 v10 = *(const bf16x8*)(Vb + lq * 128 + ((96 + hi * 16) ^ swz));
          bf16x8 v11 = *(const bf16x8*)(Vb + (32 + lq) * 128 + ((96 + hi * 16) ^ swz));
          oacc0 = __builtin_amdgcn_mfma_f32_32x32x16_bf16(pa0, v00, oacc0, 0, 0, 0);
          oacc1 = __builtin_amdgcn_mfma_f32_32x32x16_bf16(pa0, v01, oacc1, 0, 0, 0);
          oacc0 = __builtin_amdgcn_mfma_f32_32x32x16_bf16(pa1, v10, oacc0, 0, 0, 0);
          oacc1 = __builtin_amdgcn_mfma_f32_32x32x16_bf16(pa1, v11, oacc1, 0, 0, 0);
        }
      }
      bar();
    }
#pragma unroll
    for (int r = 0; r < 16; ++r) {
      int qr = (r & 3) + 8 * (r >> 2) + 4 * hi;
      float linv = 1.0f / __shfl(l_q, qr);
      size_t row = qw + qr;
      Obase[row * 1024 + lq] = (__bf16)(oacc0[r] * linv);
      Obase[row * 1024 + 32 + lq] = (__bf16)(oacc1[r] * linv);
    }
  }
}

// ---------------- launcher ----------------
extern "C" void kernel_launch(void* const* d_in, const int* in_sizes, int n_in,
                              void* d_out, int out_size, void* d_ws, size_t ws_size,
                              hipStream_t stream) {
  const float* x     = (const float*)d_in[0];
  const float* Wq    = (const float*)d_in[1];
  const float* Wk    = (const float*)d_in[2];
  const float* Wv    = (const float*)d_in[3];
  const float* Wproj = (const float*)d_in[4];
  const float* bproj = (const float*)d_in[5];
  const float* ln1_g = (const float*)d_in[6];
  const float* ln1_b = (const float*)d_in[7];
  const float* ln2_g = (const float*)d_in[8];
  const float* ln2_b = (const float*)d_in[9];
  const float* W1    = (const float*)d_in[10];
  const float* b1    = (const float*)d_in[11];
  const float* W2    = (const float*)d_in[12];
  const float* b2    = (const float*)d_in[13];
  float* out = (float*)d_out;

  char* ws = (char*)d_ws;
  __bf16* actA   = (__bf16*)(ws + 0);          // 16 MB (ln1 out, then ln2 out)
  __bf16* WqkvT  = (__bf16*)(ws + 16777216);   // 6 MB
  __bf16* WprojT = (__bf16*)(ws + 23068672);   // 2 MB
  __bf16* W1T    = (__bf16*)(ws + 25165824);   // 8 MB
  __bf16* W2T    = (__bf16*)(ws + 33554432);   // 8 MB
  __bf16* Qt     = (__bf16*)(ws + 41943040);   // 16 MB [BH][64][2048]
  __bf16* Kh     = (__bf16*)(ws + 58720256);   // 16 MB [BH][2048][64]
  __bf16* Vt     = (__bf16*)(ws + 75497472);   // 16 MB [BH][64][2048]
  __bf16* obuf   = (__bf16*)(ws + 92274688);   // 16 MB
  __bf16* ff1    = Qt;                         // 64 MB (Qt..obuf dead by then)
  __bf16* p0     = (__bf16*)(ws + 0);          // 16 MB (actA dead after FF1)
  __bf16* p1     = (__bf16*)(ws + 16777216);   // 16 MB (weights dead by FF2)

  dim3 t32x8(32, 8);
  qkv_repack<<<dim3(2, 32, 48), t32x8, 0, stream>>>(Wq, Wk, Wv, WqkvT);
  transpose_cvt<<<dim3(32, 32), t32x8, 0, stream>>>(Wproj, WprojT, 1024, 1024);
  transpose_cvt<<<dim3(128, 32), t32x8, 0, stream>>>(W1, W1T, 1024, 4096);
  transpose_cvt<<<dim3(32, 128), t32x8, 0, stream>>>(W2, W2T, 4096, 1024);

  ln_kernel<<<8192, 256, 0, stream>>>(x, ln1_g, ln1_b, actA);
  gemm2p<4><<<dim3(1536, 1, 1), 256, 0, stream>>>(actA, WqkvT, nullptr, nullptr, nullptr,
                                                  Qt, Kh, Vt, 8192, 3072, 1024, 24);
  attn_kernel4<<<dim3(8, 64), 256, 0, stream>>>(Qt, Kh, Vt, obuf);
  gemm2p<1><<<dim3(512, 1, 1), 256, 0, stream>>>(obuf, WprojT, out, bproj, x,
                                                 nullptr, nullptr, nullptr, 8192, 1024, 1024, 8);
  ln_kernel<<<8192, 256, 0, stream>>>(out, ln2_g, ln2_b, actA);
  gemm8p<2><<<dim3(512, 1, 1), 512, 0, stream>>>(actA, W1T, ff1, b1, nullptr,
                                                 nullptr, nullptr, nullptr, 8192, 4096, 1024, 16);
  gemm8p<5><<<dim3(128, 1, 2), 512, 0, stream>>>(ff1, W2T, nullptr, nullptr, nullptr,
                                                 p0, p1, nullptr, 8192, 1024, 4096, 4);
  ff2_reduce<<<8192, 256, 0, stream>>>(out, p0, p1, b2);
}

// Round 21
// 359.223 us; speedup vs baseline: 1.2885x; 1.0656x over previous
//
#include <hip/hip_runtime.h>
#include <hip/hip_bf16.h>
#include <stdint.h>

typedef __attribute__((ext_vector_type(8))) __bf16 bf16x8;
typedef __attribute__((ext_vector_type(4))) __bf16 bf16x4;
typedef __attribute__((ext_vector_type(4))) float f32x4;
typedef __attribute__((ext_vector_type(16))) float f32x16;
typedef __attribute__((ext_vector_type(4))) unsigned int u32x4;

typedef const __attribute__((address_space(1))) void* gas_ptr;
typedef __attribute__((address_space(3))) void* las_ptr;

static __device__ __forceinline__ void gload_lds16(const void* g, void* l) {
  __builtin_amdgcn_global_load_lds((gas_ptr)g, (las_ptr)l, 16, 0, 0);
}

static __device__ __forceinline__ unsigned int cvt_pk(float lo, float hi) {
  unsigned int r;
  asm("v_cvt_pk_bf16_f32 %0, %1, %2" : "=v"(r) : "v"(lo), "v"(hi));
  return r;
}

static __device__ __forceinline__ bf16x8 pack_frag(unsigned int a, unsigned int b,
                                                   unsigned int c, unsigned int d) {
  u32x4 t = {a, b, c, d};
  return __builtin_bit_cast(bf16x8, t);
}

static __device__ __forceinline__ void vm4() {
  asm volatile("s_waitcnt vmcnt(4)" ::: "memory");
}
static __device__ __forceinline__ void vm6() {
  asm volatile("s_waitcnt vmcnt(6)" ::: "memory");
}
static __device__ __forceinline__ void vm0() {
  asm volatile("s_waitcnt vmcnt(0)" ::: "memory");
}
static __device__ __forceinline__ void lgkm0sb() {
  asm volatile("s_waitcnt lgkmcnt(0)" ::: "memory");
  __builtin_amdgcn_sched_barrier(0);
}
static __device__ __forceinline__ void bar() {
  asm volatile("" ::: "memory");
  __builtin_amdgcn_s_barrier();
  asm volatile("" ::: "memory");
}

// ---------------- generic transpose + fp32->bf16 ----------------
__global__ void transpose_cvt(const float* __restrict__ in, __bf16* __restrict__ out,
                              int R, int S) {
  __shared__ float t[32][33];
  int tx = threadIdx.x, ty = threadIdx.y;
  int r0 = blockIdx.y * 32, s0 = blockIdx.x * 32;
#pragma unroll
  for (int i = 0; i < 4; ++i) {
    int r = r0 + ty + i * 8;
    if (r < R && (s0 + tx) < S) t[ty + i * 8][tx] = in[(size_t)r * S + s0 + tx];
  }
  __syncthreads();
#pragma unroll
  for (int i = 0; i < 4; ++i) {
    int s = s0 + ty + i * 8;
    if (s < S && (r0 + tx) < R) out[(size_t)s * R + r0 + tx] = (__bf16)t[tx][ty + i * 8];
  }
}

// Wq/Wk/Wv [H=16][C=1024][HS=64] -> WqkvT bf16 [3*1024 rows][1024 cols]
__global__ void qkv_repack(const float* __restrict__ Wq, const float* __restrict__ Wk,
                           const float* __restrict__ Wv, __bf16* __restrict__ outT) {
  __shared__ float t[32][33];
  int z = blockIdx.z, sel = z >> 4, h = z & 15;
  const float* in = (sel == 0 ? Wq : sel == 1 ? Wk : Wv) + (size_t)h * 1024 * 64;
  __bf16* out = outT + (size_t)(sel * 1024 + h * 64) * 1024;
  int tx = threadIdx.x, ty = threadIdx.y;
  int r0 = blockIdx.y * 32, s0 = blockIdx.x * 32;
#pragma unroll
  for (int i = 0; i < 4; ++i)
    t[ty + i * 8][tx] = in[(size_t)(r0 + ty + i * 8) * 64 + s0 + tx];
  __syncthreads();
#pragma unroll
  for (int i = 0; i < 4; ++i)
    out[(size_t)(s0 + ty + i * 8) * 1024 + r0 + tx] = (__bf16)t[tx][ty + i * 8];
}

// ---------------- LayerNorm (C=1024) -> bf16 ----------------
__global__ __launch_bounds__(256) void ln_kernel(const float* __restrict__ x,
                                                 const float* __restrict__ g,
                                                 const float* __restrict__ b,
                                                 __bf16* __restrict__ out) {
  __shared__ float red[8];
  int row = blockIdx.x, tid = threadIdx.x;
  float4 v = ((const float4*)(x + (size_t)row * 1024))[tid];
  float s = v.x + v.y + v.z + v.w;
  float s2 = v.x * v.x + v.y * v.y + v.z * v.z + v.w * v.w;
#pragma unroll
  for (int m = 1; m < 64; m <<= 1) { s += __shfl_xor(s, m); s2 += __shfl_xor(s2, m); }
  if ((tid & 63) == 0) { red[tid >> 6] = s; red[4 + (tid >> 6)] = s2; }
  __syncthreads();
  s = red[0] + red[1] + red[2] + red[3];
  s2 = red[4] + red[5] + red[6] + red[7];
  float mu = s * (1.0f / 1024.0f);
  float var = s2 * (1.0f / 1024.0f) - mu * mu;
  float rs = rsqrtf(var + 1e-5f);
  float4 gg = ((const float4*)g)[tid];
  float4 bb = ((const float4*)b)[tid];
  bf16x4 o4;
  o4[0] = (__bf16)((v.x - mu) * rs * gg.x + bb.x);
  o4[1] = (__bf16)((v.y - mu) * rs * gg.y + bb.y);
  o4[2] = (__bf16)((v.z - mu) * rs * gg.z + bb.z);
  o4[3] = (__bf16)((v.w - mu) * rs * gg.w + bb.w);
  *(bf16x4*)(out + (size_t)row * 1024 + tid * 4) = o4;
}

// -------- FF2 reduce: out += p0 + p1 + b2  (f32 out, bf16 partials) --------
__global__ __launch_bounds__(256) void ff2_reduce(float* __restrict__ out,
                                                  const __bf16* __restrict__ p0,
                                                  const __bf16* __restrict__ p1,
                                                  const float* __restrict__ b2) {
  int i = blockIdx.x * 256 + threadIdx.x;  // float4 granule
  float4 v = ((const float4*)out)[i];
  bf16x4 a = ((const bf16x4*)p0)[i];
  bf16x4 b = ((const bf16x4*)p1)[i];
  float4 bb = ((const float4*)b2)[i & 255];
  v.x += (float)a[0] + (float)b[0] + bb.x;
  v.y += (float)a[1] + (float)b[1] + bb.y;
  v.z += (float)a[2] + (float)b[2] + bb.z;
  v.w += (float)a[3] + (float)b[3] + bb.w;
  ((float4*)out)[i] = v;
}

// ============ 8-phase 256x256 GEMM (FF1, FF2) ============
// EPI 2: bf16 out = relu(acc + bias)    (FF1)
// EPI 5: bf16 partial store (split-K FF2): z==0 -> q_out, z==1 -> k_out
template <int EPI>
__global__ __launch_bounds__(512) void gemm8p(const __bf16* __restrict__ A,
                                              const __bf16* __restrict__ Bt,
                                              void* __restrict__ Cout,
                                              const float* __restrict__ bias,
                                              const float* __restrict__ resid,
                                              __bf16* __restrict__ q_out,
                                              __bf16* __restrict__ k_out,
                                              __bf16* __restrict__ vt_out,
                                              int M, int N, int K, int NBN) {
  __shared__ __align__(16) char lds[131072];
  const int tid = threadIdx.x;
  const int l = tid & 63, w = tid >> 6;
  const int wm = w >> 2, wn = w & 3;
  const int lr = l & 15, lg = l >> 4;

  int nwg = gridDim.x;
  int cpx = nwg >> 3;
  int orig = blockIdx.x;
  int wgid = (orig & 7) * cpx + (orig >> 3);
  int bn = wgid % NBN, bm = wgid / NBN;
  int n0 = bn * 256, m0 = bm * 256;

  const int Kloop = K / (int)gridDim.z;
  const int NT = Kloop >> 6;
  const size_t K2 = (size_t)K * 2;
  const size_t koff = (size_t)blockIdx.z * Kloop * 2;

  const int srow = tid >> 3, slot = tid & 7;
  const int sswz = (slot ^ (srow & 7)) << 4;
  const char* aA = (const char*)A + (size_t)(m0 + srow) * K2 + koff + sswz;
  const char* aB = (const char*)Bt + (size_t)(n0 + srow) * K2 + koff + sswz;

  auto stageA = [&](char* buf, int half, int kt) {
    char* d = buf + half * 16384 + tid * 16;
    const char* s = aA + (size_t)(half * 128) * K2 + (size_t)kt * 128;
    gload_lds16(s, d);
    gload_lds16(s + (size_t)64 * K2, d + 8192);
  };
  auto stageB = [&](char* buf, int half, int kt) {
    char* d = buf + 32768 + half * 16384 + tid * 16;
    const char* s = aB + (size_t)(half * 128) * K2 + (size_t)kt * 128;
    gload_lds16(s, d);
    gload_lds16(s + (size_t)64 * K2, d + 8192);
  };

  const int arow = (wm * 64 + lr) * 128;
  const int brow = (wn * 32 + lr) * 128;
  const int ck0 = ((lg) ^ (lr & 7)) << 4;
  const int ck1 = ((4 + lg) ^ (lr & 7)) << 4;

  f32x4 acc[8][4];
#pragma unroll
  for (int mi = 0; mi < 8; ++mi)
#pragma unroll
    for (int ni = 0; ni < 4; ++ni)
#pragma unroll
      for (int e = 0; e < 4; ++e) acc[mi][ni][e] = 0.0f;

  bf16x8 af[4][2], b0f[2][2], b1f[2][2];

  auto ldsA = [&](const char* buf, int mh) {
#pragma unroll
    for (int i = 0; i < 4; ++i) {
      const char* p = buf + mh * 16384 + arow + i * 2048;
      af[i][0] = *(const bf16x8*)(p + ck0);
      af[i][1] = *(const bf16x8*)(p + ck1);
    }
  };
  auto ldsB = [&](bf16x8 (&dst)[2][2], const char* buf, int nh) {
#pragma unroll
    for (int j = 0; j < 2; ++j) {
      const char* p = buf + 32768 + nh * 16384 + brow + j * 2048;
      dst[j][0] = *(const bf16x8*)(p + ck0);
      dst[j][1] = *(const bf16x8*)(p + ck1);
    }
  };
  auto mmq = [&](int mh, bf16x8 (&bf)[2][2], int nh) {
    __builtin_amdgcn_s_setprio(1);
#pragma unroll
    for (int i = 0; i < 4; ++i)
#pragma unroll
      for (int j = 0; j < 2; ++j) {
        int mi = mh * 4 + i, ni = nh * 2 + j;
        acc[mi][ni] = __builtin_amdgcn_mfma_f32_16x16x32_bf16(af[i][0], bf[j][0], acc[mi][ni], 0, 0, 0);
        acc[mi][ni] = __builtin_amdgcn_mfma_f32_16x16x32_bf16(af[i][1], bf[j][1], acc[mi][ni], 0, 0, 0);
      }
    __builtin_amdgcn_s_setprio(0);
  };

  char* bufE = lds;
  char* bufO = lds + 65536;

  stageA(bufE, 0, 0);
  stageB(bufE, 0, 0);
  stageB(bufE, 1, 0);
  stageA(bufE, 1, 0);
  if (NT > 1) { stageA(bufO, 0, 1); stageB(bufO, 0, 1); }
  else        { stageA(bufO, 0, 0); stageB(bufO, 0, 0); }
  vm4();
  bar();

  auto do_tile = [&](char* cur, char* oth, int t) {
    int kN = (t + 1 < NT) ? t + 1 : NT - 1;
    int kN2 = (t + 2 < NT) ? t + 2 : NT - 1;
    ldsA(cur, 0);
    ldsB(b0f, cur, 0);
    stageB(oth, 1, kN);
    bar(); lgkm0sb();
    mmq(0, b0f, 0);
    bar();
    ldsB(b1f, cur, 1);
    stageA(oth, 1, kN);
    vm6(); bar(); lgkm0sb();
    mmq(0, b1f, 1);
    bar();
    ldsA(cur, 1);
    stageA(cur, 0, kN2);
    bar(); lgkm0sb();
    mmq(1, b1f, 1);
    bar();
    stageB(cur, 0, kN2);
    vm6(); bar();
    mmq(1, b0f, 0);
    bar();
  };

  for (int t = 0; t < NT; t += 2) {
    do_tile(bufE, bufO, t);
    do_tile(bufO, bufE, t + 1);
  }

#pragma unroll
  for (int mi = 0; mi < 8; ++mi) {
    int rowb = m0 + (mi >> 2) * 128 + wm * 64 + (mi & 3) * 16 + lg * 4;
#pragma unroll
    for (int e = 0; e < 4; ++e) {
      int row = rowb + e;
#pragma unroll
      for (int ni = 0; ni < 4; ++ni) {
        int col = n0 + (ni >> 1) * 128 + wn * 32 + (ni & 1) * 16 + lr;
        float v = acc[mi][ni][e];
        size_t idx = (size_t)row * N + col;
        if (EPI == 0) {
          ((__bf16*)Cout)[idx] = (__bf16)v;
        } else if (EPI == 2) {
          v += bias[col];
          ((__bf16*)Cout)[idx] = (__bf16)fmaxf(v, 0.0f);
        } else if (EPI == 5) {
          (blockIdx.z ? k_out : q_out)[idx] = (__bf16)v;
        }
      }
    }
  }
}

// ============ 128x128 BK=32 GEMM, triple-buffer, 3 blocks/CU ============
// EPI 1: f32 out = resid + acc + bias   (proj)
// EPI 4: QKV split-scatter: Qt [BH][64][T], Kh [BH][T][64], Vt [BH][64][T]
//        Q/V (transposed outputs) go through an LDS-transpose epilogue so the
//        global writes are t-contiguous 16B chunks (full-line coverage, no
//        read-for-ownership amplification); K stays direct (semi-coalesced).
template <int EPI>
__global__ __launch_bounds__(256, 3) void gemm2p(const __bf16* __restrict__ A,
                                                 const __bf16* __restrict__ Bt,
                                                 void* __restrict__ Cout,
                                                 const float* __restrict__ bias,
                                                 const float* __restrict__ resid,
                                                 __bf16* __restrict__ q_out,
                                                 __bf16* __restrict__ k_out,
                                                 __bf16* __restrict__ vt_out,
                                                 int M, int N, int K, int NBN) {
  __shared__ __align__(16) char lds[49152];
  const int tid = threadIdx.x;
  const int l = tid & 63, w = tid >> 6;
  const int lr = l & 15, lg = l >> 4;

  int nwg = gridDim.x;
  int cpx = nwg >> 3;
  int orig = blockIdx.x;
  int wgid = (orig & 7) * cpx + (orig >> 3);
  int bn = wgid % NBN, bm = wgid / NBN;
  int n0 = bn * 128, m0 = bm * 128;

  const int Kloop = K / (int)gridDim.z;
  const int NT = Kloop >> 5;
  const size_t K2 = (size_t)K * 2;
  const size_t koff = (size_t)blockIdx.z * Kloop * 2;

  const int srow = tid >> 2;
  const int sslot = ((tid & 3) ^ ((tid >> 4) & 3)) << 4;
  const char* aA = (const char*)A + (size_t)(m0 + srow) * K2 + koff + sslot;
  const char* aB = (const char*)Bt + (size_t)(n0 + srow) * K2 + koff + sslot;

  auto stage = [&](int bufi, int kt) {
    char* d = lds + bufi * 16384 + tid * 16;
    const char* sA = aA + (size_t)kt * 64;
    const char* sB = aB + (size_t)kt * 64;
    gload_lds16(sA, d);
    gload_lds16(sA + (size_t)64 * K2, d + 4096);
    gload_lds16(sB, d + 8192);
    gload_lds16(sB + (size_t)64 * K2, d + 12288);
  };

  const int arow0 = ((w >> 1) * 64 + lr) * 64;
  const int brow0 = ((w & 1) * 64 + lr) * 64;
  const int cs = ((lg ^ (lr >> 2)) & 3) << 4;

  f32x4 acc[4][4];
#pragma unroll
  for (int mi = 0; mi < 4; ++mi)
#pragma unroll
    for (int ni = 0; ni < 4; ++ni)
#pragma unroll
      for (int e = 0; e < 4; ++e) acc[mi][ni][e] = 0.0f;

  stage(0, 0);
  stage(1, NT > 1 ? 1 : 0);
  vm4();
  bar();

  for (int t = 0; t < NT; ++t) {
    if (t + 2 < NT) stage((t + 2) % 3, t + 2);
    const char* buf = lds + (t % 3) * 16384;
    bf16x8 af[4], bfr[4];
#pragma unroll
    for (int i = 0; i < 4; ++i)
      af[i] = *(const bf16x8*)(buf + arow0 + i * 1024 + cs);
#pragma unroll
    for (int i = 0; i < 4; ++i)
      bfr[i] = *(const bf16x8*)(buf + 8192 + brow0 + i * 1024 + cs);
    lgkm0sb();
    __builtin_amdgcn_s_setprio(1);
#pragma unroll
    for (int mi = 0; mi < 4; ++mi)
#pragma unroll
      for (int ni = 0; ni < 4; ++ni)
        acc[mi][ni] = __builtin_amdgcn_mfma_f32_16x16x32_bf16(af[mi], bfr[ni], acc[mi][ni], 0, 0, 0);
    __builtin_amdgcn_s_setprio(0);
    if (t + 2 < NT) vm4(); else vm0();
    bar();
  }

  if (EPI == 4 && (n0 >> 10) != 1) {
    // ---- LDS-transpose epilogue for Q (sel 0) and V (sel 2) ----
    // staging LDS is dead (vm0+bar above); reuse as bf16 tile [128 c][136 t-pad]
    __bf16* tlds = (__bf16*)lds;
#pragma unroll
    for (int mi = 0; mi < 4; ++mi)
#pragma unroll
      for (int ni = 0; ni < 4; ++ni)
#pragma unroll
        for (int e = 0; e < 4; ++e) {
          int row = (w >> 1) * 64 + mi * 16 + lg * 4 + e;   // t-in-block
          int c = (w & 1) * 64 + ni * 16 + lr;              // col-in-block
          tlds[c * 136 + row] = (__bf16)acc[mi][ni][e];
        }
    bar();
    int c = tid >> 1, th = (tid & 1) * 64;
    int colg = n0 + c;
    int cc = colg & 1023, h = cc >> 6, d = cc & 63;
    int bb2 = m0 >> 11, t0 = m0 & 2047;  // block-uniform (BM=128 divides T)
    int sel = n0 >> 10;
    __bf16* dst = (sel == 0 ? q_out : vt_out) +
                  (((size_t)(bb2 * 16 + h)) * 64 + d) * 2048 + t0 + th;
    const __bf16* src = tlds + c * 136 + th;
#pragma unroll
    for (int k = 0; k < 8; ++k)
      *(bf16x8*)(dst + k * 8) = *(const bf16x8*)(src + k * 8);
  } else {
#pragma unroll
    for (int mi = 0; mi < 4; ++mi) {
      int rowb = m0 + (w >> 1) * 64 + mi * 16 + lg * 4;
#pragma unroll
      for (int e = 0; e < 4; ++e) {
        int row = rowb + e;
#pragma unroll
        for (int ni = 0; ni < 4; ++ni) {
          int col = n0 + (w & 1) * 64 + ni * 16 + lr;
          float v = acc[mi][ni][e];
          size_t idx = (size_t)row * N + col;
          if (EPI == 1) {
            ((float*)Cout)[idx] = resid[idx] + v + bias[col];
          } else if (EPI == 0) {
            ((__bf16*)Cout)[idx] = (__bf16)v;
          } else {  // EPI 4, sel==1: K row-major direct store
            int b = row >> 11, t2 = row & 2047;
            int cc = col & 1023, h = cc >> 6, d = cc & 63;
            int bh = b * 16 + h;
            k_out[((size_t)bh * 2048 + t2) * 64 + d] = (__bf16)v;
          }
        }
      }
    }
  }
}

// ---------------- causal flash attention v4 (dbuf staging) ------------------
// 4 waves/block, 32 q/wave (QBLK=128), KVBLK=64, double-buffered K/V LDS with
// counted vmcnt. Block handles q-tile pair (p, 15-p) -> uniform 34 kv-tiles.
// Qt: [BH][64][2048]  Kh: [BH][2048][64]  Vt: [BH][64][2048]  o: [B][T][1024]
__global__ __launch_bounds__(256) void attn_kernel4(const __bf16* __restrict__ Qt,
                                                    const __bf16* __restrict__ Kh,
                                                    const __bf16* __restrict__ Vt,
                                                    __bf16* __restrict__ o) {
  __shared__ __align__(16) char Klds[16384];  // 2 x 64 keys x 128B, swizzled
  __shared__ __align__(16) char Vlds[16384];  // 2 x 64 dims x 128B, swizzled
  int tid = threadIdx.x;
  int l = tid & 63, w = tid >> 6;
  int lq = l & 31, hi = l >> 5;
  int p = blockIdx.x, bh = blockIdx.y;
  int b = bh >> 4, h = bh & 15;

  const char* Kbase = (const char*)(Kh + (size_t)bh * 2048 * 64);
  const char* Vbase = (const char*)(Vt + (size_t)bh * 64 * 2048);
  const __bf16* Qbase = Qt + (size_t)bh * 64 * 2048;
  __bf16* Obase = o + (size_t)b * 2048 * 1024 + h * 64;

  int srow = tid >> 3;
  int schunk = (tid & 7) * 16;
  int sw0 = (srow & 7) << 4;
  int swz = (lq & 7) << 4;

  auto stageKV = [&](int bufi, int s0) {
    char* kd = Klds + bufi * 8192 + tid * 16;
    char* vd = Vlds + bufi * 8192 + tid * 16;
    gload_lds16(Kbase + (size_t)(s0 + srow) * 128 + (schunk ^ sw0), kd);
    gload_lds16(Kbase + (size_t)(s0 + srow + 32) * 128 + (schunk ^ sw0), kd + 4096);
    gload_lds16(Vbase + (size_t)srow * 4096 + s0 * 2 + (schunk ^ sw0), vd);
    gload_lds16(Vbase + (size_t)(srow + 32) * 4096 + s0 * 2 + (schunk ^ sw0), vd + 4096);
  };

  for (int sweep = 0; sweep < 2; ++sweep) {
    int t = (sweep == 0) ? p : 15 - p;
    int qw = t * 128 + w * 32;
    int qglob = qw + lq;

    // Q B-fragments: qb[s][j] = Q[hs = s*16 + hi*8 + j][qw + lq]
    bf16x8 qb[4];
    const __bf16* qsrc = Qbase + (size_t)(hi * 8) * 2048 + qw + lq;
#pragma unroll
    for (int s = 0; s < 4; ++s)
#pragma unroll
      for (int j = 0; j < 8; ++j)
        qb[s][j] = qsrc[(size_t)(s * 16 + j) * 2048];

    f32x16 oacc0, oacc1;
#pragma unroll
    for (int i = 0; i < 16; ++i) { oacc0[i] = 0.0f; oacc1[i] = 0.0f; }
    float m_q = -3.0e38f, l_q = 0.0f;

    int nkb = 2 * t + 2;
    stageKV(0, 0);
    for (int kb = 0; kb < nkb; ++kb) {
      int s0 = kb * 64;
      if (kb + 1 < nkb) { stageKV((kb + 1) & 1, s0 + 64); vm4(); }
      else vm0();
      bar();
      const char* Kb = Klds + (kb & 1) * 8192;
      const char* Vb = Vlds + (kb & 1) * 8192;

      if (s0 <= qw + 31) {  // else: tile fully masked for this wave
        f32x16 st0, st1;
#pragma unroll
        for (int i = 0; i < 16; ++i) { st0[i] = 0.0f; st1[i] = 0.0f; }
#pragma unroll
        for (int s = 0; s < 4; ++s) {
          bf16x8 ka = *(const bf16x8*)(Kb + lq * 128 + ((s * 32 + hi * 16) ^ swz));
          st0 = __builtin_amdgcn_mfma_f32_32x32x16_bf16(ka, qb[s], st0, 0, 0, 0);
        }
#pragma unroll
        for (int s = 0; s < 4; ++s) {
          bf16x8 ka = *(const bf16x8*)(Kb + (32 + lq) * 128 + ((s * 32 + hi * 16) ^ swz));
          st1 = __builtin_amdgcn_mfma_f32_32x32x16_bf16(ka, qb[s], st1, 0, 0, 0);
        }
        if (s0 + 63 > qw) {  // diagonal tiles only
#pragma unroll
          for (int r = 0; r < 16; ++r) {
            int key0 = s0 + (r & 3) + 8 * (r >> 2) + 4 * hi;
            if (key0 > qglob) st0[r] = -1.0e38f;
            if (key0 + 32 > qglob) st1[r] = -1.0e38f;
          }
        }
        float mx8[8];
#pragma unroll
        for (int i = 0; i < 8; ++i)
          mx8[i] = fmaxf(fmaxf(st0[i], st0[i + 8]), fmaxf(st1[i], st1[i + 8]));
        float mx = fmaxf(fmaxf(fmaxf(mx8[0], mx8[1]), fmaxf(mx8[2], mx8[3])),
                         fmaxf(fmaxf(mx8[4], mx8[5]), fmaxf(mx8[6], mx8[7])));
        {
          float u = mx, v = mx;
          asm("v_permlane32_swap_b32 %0, %1" : "+v"(u), "+v"(v));
          mx = fmaxf(u, v);
        }
        float mt_s = mx * 0.03125f;
        if (__any(mt_s > m_q + 8.0f)) {
          float mnew = fmaxf(m_q, mt_s);
          float scv = exp2f((m_q - mnew) * 1.44269504f);
          m_q = mnew;
          l_q *= scv;
#pragma unroll
          for (int r = 0; r < 16; ++r) {
            int qr = (r & 3) + 8 * (r >> 2) + 4 * hi;
            float scO = __shfl(scv, qr);
            oacc0[r] *= scO;
            oacc1[r] *= scO;
          }
        }
        float m2 = m_q * 1.44269504f;
#pragma unroll
        for (int r = 0; r < 16; ++r) {
          st0[r] = exp2f(fmaf(st0[r], 0.045084389f, -m2));
          st1[r] = exp2f(fmaf(st1[r], 0.045084389f, -m2));
        }
        float s8[8];
#pragma unroll
        for (int i = 0; i < 8; ++i)
          s8[i] = (st0[i] + st0[i + 8]) + (st1[i] + st1[i + 8]);
        float ps = ((s8[0] + s8[1]) + (s8[2] + s8[3])) +
                   ((s8[4] + s8[5]) + (s8[6] + s8[7]));
        {
          float u = ps, v = ps;
          asm("v_permlane32_swap_b32 %0, %1" : "+v"(u), "+v"(v));
          ps = u + v;
        }
        l_q += ps;

        {
          unsigned int w0 = cvt_pk(st0[0], st0[1]), w1 = cvt_pk(st0[2], st0[3]);
          unsigned int w2 = cvt_pk(st0[4], st0[5]), w3 = cvt_pk(st0[6], st0[7]);
          asm("v_permlane32_swap_b32 %0, %1" : "+v"(w0), "+v"(w2));
          asm("v_permlane32_swap_b32 %0, %1" : "+v"(w1), "+v"(w3));
          bf16x8 pa0 = pack_frag(w0, w1, w2, w3);
          unsigned int w4 = cvt_pk(st0[8], st0[9]), w5 = cvt_pk(st0[10], st0[11]);
          unsigned int w6 = cvt_pk(st0[12], st0[13]), w7 = cvt_pk(st0[14], st0[15]);
          asm("v_permlane32_swap_b32 %0, %1" : "+v"(w4), "+v"(w6));
          asm("v_permlane32_swap_b32 %0, %1" : "+v"(w5), "+v"(w7));
          bf16x8 pa1 = pack_frag(w4, w5, w6, w7);
          bf16x8 v00 = *(const bf16x8*)(Vb + lq * 128 + ((hi * 16) ^ swz));
          bf16x8 v01 = *(const bf16x8*)(Vb + (32 + lq) * 128 + ((hi * 16) ^ swz));
          bf16x8 v10 = *(const bf16x8*)(Vb + lq * 128 + ((32 + hi * 16) ^ swz));
          bf16x8 v11 = *(const bf16x8*)(Vb + (32 + lq) * 128 + ((32 + hi * 16) ^ swz));
          oacc0 = __builtin_amdgcn_mfma_f32_32x32x16_bf16(pa0, v00, oacc0, 0, 0, 0);
          oacc1 = __builtin_amdgcn_mfma_f32_32x32x16_bf16(pa0, v01, oacc1, 0, 0, 0);
          oacc0 = __builtin_amdgcn_mfma_f32_32x32x16_bf16(pa1, v10, oacc0, 0, 0, 0);
          oacc1 = __builtin_amdgcn_mfma_f32_32x32x16_bf16(pa1, v11, oacc1, 0, 0, 0);
        }
        {
          unsigned int w0 = cvt_pk(st1[0], st1[1]), w1 = cvt_pk(st1[2], st1[3]);
          unsigned int w2 = cvt_pk(st1[4], st1[5]), w3 = cvt_pk(st1[6], st1[7]);
          asm("v_permlane32_swap_b32 %0, %1" : "+v"(w0), "+v"(w2));
          asm("v_permlane32_swap_b32 %0, %1" : "+v"(w1), "+v"(w3));
          bf16x8 pa0 = pack_frag(w0, w1, w2, w3);
          unsigned int w4 = cvt_pk(st1[8], st1[9]), w5 = cvt_pk(st1[10], st1[11]);
          unsigned int w6 = cvt_pk(st1[12], st1[13]), w7 = cvt_pk(st1[14], st1[15]);
          asm("v_permlane32_swap_b32 %0, %1" : "+v"(w4), "+v"(w6));
          asm("v_permlane32_swap_b32 %0, %1" : "+v"(w5), "+v"(w7));
          bf16x8 pa1 = pack_frag(w4, w5, w6, w7);
          bf16x8 v00 = *(const bf16x8*)(Vb + lq * 128 + ((64 + hi * 16) ^ swz));
          bf16x8 v01 = *(const bf16x8*)(Vb + (32 + lq) * 128 + ((64 + hi * 16) ^ swz));
          bf16x8 v10 = *(const bf16x8*)(Vb + lq * 128 + ((96 + hi * 16) ^ swz));
          bf16x8 v11 = *(const bf16x8*)(Vb + (32 + lq) * 128 + ((96 + hi * 16) ^ swz));
          oacc0 = __builtin_amdgcn_mfma_f32_32x32x16_bf16(pa0, v00, oacc0, 0, 0, 0);
          oacc1 = __builtin_amdgcn_mfma_f32_32x32x16_bf16(pa0, v01, oacc1, 0, 0, 0);
          oacc0 = __builtin_amdgcn_mfma_f32_32x32x16_bf16(pa1, v10, oacc0, 0, 0, 0);
          oacc1 = __builtin_amdgcn_mfma_f32_32x32x16_bf16(pa1, v11, oacc1, 0, 0, 0);
        }
      }
      bar();
    }
#pragma unroll
    for (int r = 0; r < 16; ++r) {
      int qr = (r & 3) + 8 * (r >> 2) + 4 * hi;
      float linv = 1.0f / __shfl(l_q, qr);
      size_t row = qw + qr;
      Obase[row * 1024 + lq] = (__bf16)(oacc0[r] * linv);
      Obase[row * 1024 + 32 + lq] = (__bf16)(oacc1[r] * linv);
    }
  }
}

// ---------------- launcher ----------------
extern "C" void kernel_launch(void* const* d_in, const int* in_sizes, int n_in,
                              void* d_out, int out_size, void* d_ws, size_t ws_size,
                              hipStream_t stream) {
  const float* x     = (const float*)d_in[0];
  const float* Wq    = (const float*)d_in[1];
  const float* Wk    = (const float*)d_in[2];
  const float* Wv    = (const float*)d_in[3];
  const float* Wproj = (const float*)d_in[4];
  const float* bproj = (const float*)d_in[5];
  const float* ln1_g = (const float*)d_in[6];
  const float* ln1_b = (const float*)d_in[7];
  const float* ln2_g = (const float*)d_in[8];
  const float* ln2_b = (const float*)d_in[9];
  const float* W1    = (const float*)d_in[10];
  const float* b1    = (const float*)d_in[11];
  const float* W2    = (const float*)d_in[12];
  const float* b2    = (const float*)d_in[13];
  float* out = (float*)d_out;

  char* ws = (char*)d_ws;
  __bf16* actA   = (__bf16*)(ws + 0);          // 16 MB (ln1 out, then ln2 out)
  __bf16* WqkvT  = (__bf16*)(ws + 16777216);   // 6 MB
  __bf16* WprojT = (__bf16*)(ws + 23068672);   // 2 MB
  __bf16* W1T    = (__bf16*)(ws + 25165824);   // 8 MB
  __bf16* W2T    = (__bf16*)(ws + 33554432);   // 8 MB
  __bf16* Qt     = (__bf16*)(ws + 41943040);   // 16 MB [BH][64][2048]
  __bf16* Kh     = (__bf16*)(ws + 58720256);   // 16 MB [BH][2048][64]
  __bf16* Vt     = (__bf16*)(ws + 75497472);   // 16 MB [BH][64][2048]
  __bf16* obuf   = (__bf16*)(ws + 92274688);   // 16 MB
  __bf16* ff1    = Qt;                         // 64 MB (Qt..obuf dead by then)
  __bf16* p0     = (__bf16*)(ws + 0);          // 16 MB (actA dead after FF1)
  __bf16* p1     = (__bf16*)(ws + 16777216);   // 16 MB (weights dead by FF2)

  dim3 t32x8(32, 8);
  qkv_repack<<<dim3(2, 32, 48), t32x8, 0, stream>>>(Wq, Wk, Wv, WqkvT);
  transpose_cvt<<<dim3(32, 32), t32x8, 0, stream>>>(Wproj, WprojT, 1024, 1024);
  transpose_cvt<<<dim3(128, 32), t32x8, 0, stream>>>(W1, W1T, 1024, 4096);
  transpose_cvt<<<dim3(32, 128), t32x8, 0, stream>>>(W2, W2T, 4096, 1024);

  ln_kernel<<<8192, 256, 0, stream>>>(x, ln1_g, ln1_b, actA);
  gemm2p<4><<<dim3(1536, 1, 1), 256, 0, stream>>>(actA, WqkvT, nullptr, nullptr, nullptr,
                                                  Qt, Kh, Vt, 8192, 3072, 1024, 24);
  attn_kernel4<<<dim3(8, 64), 256, 0, stream>>>(Qt, Kh, Vt, obuf);
  gemm2p<1><<<dim3(512, 1, 1), 256, 0, stream>>>(obuf, WprojT, out, bproj, x,
                                                 nullptr, nullptr, nullptr, 8192, 1024, 1024, 8);
  ln_kernel<<<8192, 256, 0, stream>>>(out, ln2_g, ln2_b, actA);
  gemm8p<2><<<dim3(512, 1, 1), 512, 0, stream>>>(actA, W1T, ff1, b1, nullptr,
                                                 nullptr, nullptr, nullptr, 8192, 4096, 1024, 16);
  gemm8p<5><<<dim3(128, 1, 2), 512, 0, stream>>>(ff1, W2T, nullptr, nullptr, nullptr,
                                                 p0, p1, nullptr, 8192, 1024, 4096, 4);
  ff2_reduce<<<8192, 256, 0, stream>>>(out, p0, p1, b2);
}

// Round 22
// 354.918 us; speedup vs baseline: 1.3041x; 1.0121x over previous
//
#include <hip/hip_runtime.h>
#include <hip/hip_bf16.h>
#include <stdint.h>

typedef __attribute__((ext_vector_type(8))) __bf16 bf16x8;
typedef __attribute__((ext_vector_type(4))) __bf16 bf16x4;
typedef __attribute__((ext_vector_type(4))) float f32x4;
typedef __attribute__((ext_vector_type(16))) float f32x16;
typedef __attribute__((ext_vector_type(4))) unsigned int u32x4;

typedef const __attribute__((address_space(1))) void* gas_ptr;
typedef __attribute__((address_space(3))) void* las_ptr;

static __device__ __forceinline__ void gload_lds16(const void* g, void* l) {
  __builtin_amdgcn_global_load_lds((gas_ptr)g, (las_ptr)l, 16, 0, 0);
}

static __device__ __forceinline__ unsigned int cvt_pk(float lo, float hi) {
  unsigned int r;
  asm("v_cvt_pk_bf16_f32 %0, %1, %2" : "=v"(r) : "v"(lo), "v"(hi));
  return r;
}

static __device__ __forceinline__ bf16x8 pack_frag(unsigned int a, unsigned int b,
                                                   unsigned int c, unsigned int d) {
  u32x4 t = {a, b, c, d};
  return __builtin_bit_cast(bf16x8, t);
}

static __device__ __forceinline__ void vm4() {
  asm volatile("s_waitcnt vmcnt(4)" ::: "memory");
}
static __device__ __forceinline__ void vm6() {
  asm volatile("s_waitcnt vmcnt(6)" ::: "memory");
}
static __device__ __forceinline__ void vm0() {
  asm volatile("s_waitcnt vmcnt(0)" ::: "memory");
}
static __device__ __forceinline__ void lgkm0sb() {
  asm volatile("s_waitcnt lgkmcnt(0)" ::: "memory");
  __builtin_amdgcn_sched_barrier(0);
}
static __device__ __forceinline__ void bar() {
  asm volatile("" ::: "memory");
  __builtin_amdgcn_s_barrier();
  asm volatile("" ::: "memory");
}

// ---------------- generic transpose + fp32->bf16 ----------------
__global__ void transpose_cvt(const float* __restrict__ in, __bf16* __restrict__ out,
                              int R, int S) {
  __shared__ float t[32][33];
  int tx = threadIdx.x, ty = threadIdx.y;
  int r0 = blockIdx.y * 32, s0 = blockIdx.x * 32;
#pragma unroll
  for (int i = 0; i < 4; ++i) {
    int r = r0 + ty + i * 8;
    if (r < R && (s0 + tx) < S) t[ty + i * 8][tx] = in[(size_t)r * S + s0 + tx];
  }
  __syncthreads();
#pragma unroll
  for (int i = 0; i < 4; ++i) {
    int s = s0 + ty + i * 8;
    if (s < S && (r0 + tx) < R) out[(size_t)s * R + r0 + tx] = (__bf16)t[tx][ty + i * 8];
  }
}

// Wq/Wk/Wv [H=16][C=1024][HS=64] -> WqkvT bf16 [3*1024 rows][1024 cols]
__global__ void qkv_repack(const float* __restrict__ Wq, const float* __restrict__ Wk,
                           const float* __restrict__ Wv, __bf16* __restrict__ outT) {
  __shared__ float t[32][33];
  int z = blockIdx.z, sel = z >> 4, h = z & 15;
  const float* in = (sel == 0 ? Wq : sel == 1 ? Wk : Wv) + (size_t)h * 1024 * 64;
  __bf16* out = outT + (size_t)(sel * 1024 + h * 64) * 1024;
  int tx = threadIdx.x, ty = threadIdx.y;
  int r0 = blockIdx.y * 32, s0 = blockIdx.x * 32;
#pragma unroll
  for (int i = 0; i < 4; ++i)
    t[ty + i * 8][tx] = in[(size_t)(r0 + ty + i * 8) * 64 + s0 + tx];
  __syncthreads();
#pragma unroll
  for (int i = 0; i < 4; ++i)
    out[(size_t)(s0 + ty + i * 8) * 1024 + r0 + tx] = (__bf16)t[tx][ty + i * 8];
}

// ---------------- LayerNorm (C=1024) -> bf16 ----------------
__global__ __launch_bounds__(256) void ln_kernel(const float* __restrict__ x,
                                                 const float* __restrict__ g,
                                                 const float* __restrict__ b,
                                                 __bf16* __restrict__ out) {
  __shared__ float red[8];
  int row = blockIdx.x, tid = threadIdx.x;
  float4 v = ((const float4*)(x + (size_t)row * 1024))[tid];
  float s = v.x + v.y + v.z + v.w;
  float s2 = v.x * v.x + v.y * v.y + v.z * v.z + v.w * v.w;
#pragma unroll
  for (int m = 1; m < 64; m <<= 1) { s += __shfl_xor(s, m); s2 += __shfl_xor(s2, m); }
  if ((tid & 63) == 0) { red[tid >> 6] = s; red[4 + (tid >> 6)] = s2; }
  __syncthreads();
  s = red[0] + red[1] + red[2] + red[3];
  s2 = red[4] + red[5] + red[6] + red[7];
  float mu = s * (1.0f / 1024.0f);
  float var = s2 * (1.0f / 1024.0f) - mu * mu;
  float rs = rsqrtf(var + 1e-5f);
  float4 gg = ((const float4*)g)[tid];
  float4 bb = ((const float4*)b)[tid];
  bf16x4 o4;
  o4[0] = (__bf16)((v.x - mu) * rs * gg.x + bb.x);
  o4[1] = (__bf16)((v.y - mu) * rs * gg.y + bb.y);
  o4[2] = (__bf16)((v.z - mu) * rs * gg.z + bb.z);
  o4[3] = (__bf16)((v.w - mu) * rs * gg.w + bb.w);
  *(bf16x4*)(out + (size_t)row * 1024 + tid * 4) = o4;
}

// -------- FF2 reduce: out += p0 + p1 + b2  (f32 out, bf16 partials) --------
__global__ __launch_bounds__(256) void ff2_reduce(float* __restrict__ out,
                                                  const __bf16* __restrict__ p0,
                                                  const __bf16* __restrict__ p1,
                                                  const float* __restrict__ b2) {
  int i = blockIdx.x * 256 + threadIdx.x;  // float4 granule
  float4 v = ((const float4*)out)[i];
  bf16x4 a = ((const bf16x4*)p0)[i];
  bf16x4 b = ((const bf16x4*)p1)[i];
  float4 bb = ((const float4*)b2)[i & 255];
  v.x += (float)a[0] + (float)b[0] + bb.x;
  v.y += (float)a[1] + (float)b[1] + bb.y;
  v.z += (float)a[2] + (float)b[2] + bb.z;
  v.w += (float)a[3] + (float)b[3] + bb.w;
  ((float4*)out)[i] = v;
}

// ============ 8-phase 256x256 GEMM (FF1, FF2) ============
// EPI 2: bf16 out = relu(acc + bias)    (FF1)
// EPI 5: bf16 partial store (split-K FF2): z==0 -> q_out, z==1 -> k_out
template <int EPI>
__global__ __launch_bounds__(512) void gemm8p(const __bf16* __restrict__ A,
                                              const __bf16* __restrict__ Bt,
                                              void* __restrict__ Cout,
                                              const float* __restrict__ bias,
                                              const float* __restrict__ resid,
                                              __bf16* __restrict__ q_out,
                                              __bf16* __restrict__ k_out,
                                              __bf16* __restrict__ vt_out,
                                              int M, int N, int K, int NBN) {
  __shared__ __align__(16) char lds[131072];
  const int tid = threadIdx.x;
  const int l = tid & 63, w = tid >> 6;
  const int wm = w >> 2, wn = w & 3;
  const int lr = l & 15, lg = l >> 4;

  int nwg = gridDim.x;
  int cpx = nwg >> 3;
  int orig = blockIdx.x;
  int wgid = (orig & 7) * cpx + (orig >> 3);
  int bn = wgid % NBN, bm = wgid / NBN;
  int n0 = bn * 256, m0 = bm * 256;

  const int Kloop = K / (int)gridDim.z;
  const int NT = Kloop >> 6;
  const size_t K2 = (size_t)K * 2;
  const size_t koff = (size_t)blockIdx.z * Kloop * 2;

  const int srow = tid >> 3, slot = tid & 7;
  const int sswz = (slot ^ (srow & 7)) << 4;
  const char* aA = (const char*)A + (size_t)(m0 + srow) * K2 + koff + sswz;
  const char* aB = (const char*)Bt + (size_t)(n0 + srow) * K2 + koff + sswz;

  auto stageA = [&](char* buf, int half, int kt) {
    char* d = buf + half * 16384 + tid * 16;
    const char* s = aA + (size_t)(half * 128) * K2 + (size_t)kt * 128;
    gload_lds16(s, d);
    gload_lds16(s + (size_t)64 * K2, d + 8192);
  };
  auto stageB = [&](char* buf, int half, int kt) {
    char* d = buf + 32768 + half * 16384 + tid * 16;
    const char* s = aB + (size_t)(half * 128) * K2 + (size_t)kt * 128;
    gload_lds16(s, d);
    gload_lds16(s + (size_t)64 * K2, d + 8192);
  };

  const int arow = (wm * 64 + lr) * 128;
  const int brow = (wn * 32 + lr) * 128;
  const int ck0 = ((lg) ^ (lr & 7)) << 4;
  const int ck1 = ((4 + lg) ^ (lr & 7)) << 4;

  f32x4 acc[8][4];
#pragma unroll
  for (int mi = 0; mi < 8; ++mi)
#pragma unroll
    for (int ni = 0; ni < 4; ++ni)
#pragma unroll
      for (int e = 0; e < 4; ++e) acc[mi][ni][e] = 0.0f;

  bf16x8 af[4][2], b0f[2][2], b1f[2][2];

  auto ldsA = [&](const char* buf, int mh) {
#pragma unroll
    for (int i = 0; i < 4; ++i) {
      const char* p = buf + mh * 16384 + arow + i * 2048;
      af[i][0] = *(const bf16x8*)(p + ck0);
      af[i][1] = *(const bf16x8*)(p + ck1);
    }
  };
  auto ldsB = [&](bf16x8 (&dst)[2][2], const char* buf, int nh) {
#pragma unroll
    for (int j = 0; j < 2; ++j) {
      const char* p = buf + 32768 + nh * 16384 + brow + j * 2048;
      dst[j][0] = *(const bf16x8*)(p + ck0);
      dst[j][1] = *(const bf16x8*)(p + ck1);
    }
  };
  auto mmq = [&](int mh, bf16x8 (&bf)[2][2], int nh) {
    __builtin_amdgcn_s_setprio(1);
#pragma unroll
    for (int i = 0; i < 4; ++i)
#pragma unroll
      for (int j = 0; j < 2; ++j) {
        int mi = mh * 4 + i, ni = nh * 2 + j;
        acc[mi][ni] = __builtin_amdgcn_mfma_f32_16x16x32_bf16(af[i][0], bf[j][0], acc[mi][ni], 0, 0, 0);
        acc[mi][ni] = __builtin_amdgcn_mfma_f32_16x16x32_bf16(af[i][1], bf[j][1], acc[mi][ni], 0, 0, 0);
      }
    __builtin_amdgcn_s_setprio(0);
  };

  char* bufE = lds;
  char* bufO = lds + 65536;

  stageA(bufE, 0, 0);
  stageB(bufE, 0, 0);
  stageB(bufE, 1, 0);
  stageA(bufE, 1, 0);
  if (NT > 1) { stageA(bufO, 0, 1); stageB(bufO, 0, 1); }
  else        { stageA(bufO, 0, 0); stageB(bufO, 0, 0); }
  vm4();
  bar();

  auto do_tile = [&](char* cur, char* oth, int t) {
    int kN = (t + 1 < NT) ? t + 1 : NT - 1;
    int kN2 = (t + 2 < NT) ? t + 2 : NT - 1;
    ldsA(cur, 0);
    ldsB(b0f, cur, 0);
    stageB(oth, 1, kN);
    bar(); lgkm0sb();
    mmq(0, b0f, 0);
    bar();
    ldsB(b1f, cur, 1);
    stageA(oth, 1, kN);
    vm6(); bar(); lgkm0sb();
    mmq(0, b1f, 1);
    bar();
    ldsA(cur, 1);
    stageA(cur, 0, kN2);
    bar(); lgkm0sb();
    mmq(1, b1f, 1);
    bar();
    stageB(cur, 0, kN2);
    vm6(); bar();
    mmq(1, b0f, 0);
    bar();
  };

  for (int t = 0; t < NT; t += 2) {
    do_tile(bufE, bufO, t);
    do_tile(bufO, bufE, t + 1);
  }

#pragma unroll
  for (int mi = 0; mi < 8; ++mi) {
    int rowb = m0 + (mi >> 2) * 128 + wm * 64 + (mi & 3) * 16 + lg * 4;
#pragma unroll
    for (int e = 0; e < 4; ++e) {
      int row = rowb + e;
#pragma unroll
      for (int ni = 0; ni < 4; ++ni) {
        int col = n0 + (ni >> 1) * 128 + wn * 32 + (ni & 1) * 16 + lr;
        float v = acc[mi][ni][e];
        size_t idx = (size_t)row * N + col;
        if (EPI == 0) {
          ((__bf16*)Cout)[idx] = (__bf16)v;
        } else if (EPI == 2) {
          v += bias[col];
          ((__bf16*)Cout)[idx] = (__bf16)fmaxf(v, 0.0f);
        } else if (EPI == 5) {
          (blockIdx.z ? k_out : q_out)[idx] = (__bf16)v;
        }
      }
    }
  }
}

// ============ 128x128 BK=32 GEMM, triple-buffer, 3 blocks/CU ============
// EPI 1: f32 out = resid + acc + bias   (proj)
// EPI 4: QKV split-scatter: Qt [BH][64][T], Kh [BH][T][64], Vt [BH][64][T]
//        Q/V (transposed outputs) go through an LDS-transpose epilogue so the
//        global writes are t-contiguous 16B chunks; K stays direct.
template <int EPI>
__global__ __launch_bounds__(256, 3) void gemm2p(const __bf16* __restrict__ A,
                                                 const __bf16* __restrict__ Bt,
                                                 void* __restrict__ Cout,
                                                 const float* __restrict__ bias,
                                                 const float* __restrict__ resid,
                                                 __bf16* __restrict__ q_out,
                                                 __bf16* __restrict__ k_out,
                                                 __bf16* __restrict__ vt_out,
                                                 int M, int N, int K, int NBN) {
  __shared__ __align__(16) char lds[49152];
  const int tid = threadIdx.x;
  const int l = tid & 63, w = tid >> 6;
  const int lr = l & 15, lg = l >> 4;

  int nwg = gridDim.x;
  int cpx = nwg >> 3;
  int orig = blockIdx.x;
  int wgid = (orig & 7) * cpx + (orig >> 3);
  int bn = wgid % NBN, bm = wgid / NBN;
  int n0 = bn * 128, m0 = bm * 128;

  const int Kloop = K / (int)gridDim.z;
  const int NT = Kloop >> 5;
  const size_t K2 = (size_t)K * 2;
  const size_t koff = (size_t)blockIdx.z * Kloop * 2;

  const int srow = tid >> 2;
  const int sslot = ((tid & 3) ^ ((tid >> 4) & 3)) << 4;
  const char* aA = (const char*)A + (size_t)(m0 + srow) * K2 + koff + sslot;
  const char* aB = (const char*)Bt + (size_t)(n0 + srow) * K2 + koff + sslot;

  auto stage = [&](int bufi, int kt) {
    char* d = lds + bufi * 16384 + tid * 16;
    const char* sA = aA + (size_t)kt * 64;
    const char* sB = aB + (size_t)kt * 64;
    gload_lds16(sA, d);
    gload_lds16(sA + (size_t)64 * K2, d + 4096);
    gload_lds16(sB, d + 8192);
    gload_lds16(sB + (size_t)64 * K2, d + 12288);
  };

  const int arow0 = ((w >> 1) * 64 + lr) * 64;
  const int brow0 = ((w & 1) * 64 + lr) * 64;
  const int cs = ((lg ^ (lr >> 2)) & 3) << 4;

  f32x4 acc[4][4];
#pragma unroll
  for (int mi = 0; mi < 4; ++mi)
#pragma unroll
    for (int ni = 0; ni < 4; ++ni)
#pragma unroll
      for (int e = 0; e < 4; ++e) acc[mi][ni][e] = 0.0f;

  stage(0, 0);
  stage(1, NT > 1 ? 1 : 0);
  vm4();
  bar();

  for (int t = 0; t < NT; ++t) {
    if (t + 2 < NT) stage((t + 2) % 3, t + 2);
    const char* buf = lds + (t % 3) * 16384;
    bf16x8 af[4], bfr[4];
#pragma unroll
    for (int i = 0; i < 4; ++i)
      af[i] = *(const bf16x8*)(buf + arow0 + i * 1024 + cs);
#pragma unroll
    for (int i = 0; i < 4; ++i)
      bfr[i] = *(const bf16x8*)(buf + 8192 + brow0 + i * 1024 + cs);
    lgkm0sb();
    __builtin_amdgcn_s_setprio(1);
#pragma unroll
    for (int mi = 0; mi < 4; ++mi)
#pragma unroll
      for (int ni = 0; ni < 4; ++ni)
        acc[mi][ni] = __builtin_amdgcn_mfma_f32_16x16x32_bf16(af[mi], bfr[ni], acc[mi][ni], 0, 0, 0);
    __builtin_amdgcn_s_setprio(0);
    if (t + 2 < NT) vm4(); else vm0();
    bar();
  }

  if (EPI == 4 && (n0 >> 10) != 1) {
    // ---- LDS-transpose epilogue for Q (sel 0) and V (sel 2) ----
    __bf16* tlds = (__bf16*)lds;
#pragma unroll
    for (int mi = 0; mi < 4; ++mi)
#pragma unroll
      for (int ni = 0; ni < 4; ++ni)
#pragma unroll
        for (int e = 0; e < 4; ++e) {
          int row = (w >> 1) * 64 + mi * 16 + lg * 4 + e;   // t-in-block
          int c = (w & 1) * 64 + ni * 16 + lr;              // col-in-block
          tlds[c * 136 + row] = (__bf16)acc[mi][ni][e];
        }
    bar();
    int c = tid >> 1, th = (tid & 1) * 64;
    int colg = n0 + c;
    int cc = colg & 1023, h = cc >> 6, d = cc & 63;
    int bb2 = m0 >> 11, t0 = m0 & 2047;  // block-uniform (BM=128 divides T)
    int sel = n0 >> 10;
    __bf16* dst = (sel == 0 ? q_out : vt_out) +
                  (((size_t)(bb2 * 16 + h)) * 64 + d) * 2048 + t0 + th;
    const __bf16* src = tlds + c * 136 + th;
#pragma unroll
    for (int k = 0; k < 8; ++k)
      *(bf16x8*)(dst + k * 8) = *(const bf16x8*)(src + k * 8);
  } else {
#pragma unroll
    for (int mi = 0; mi < 4; ++mi) {
      int rowb = m0 + (w >> 1) * 64 + mi * 16 + lg * 4;
#pragma unroll
      for (int e = 0; e < 4; ++e) {
        int row = rowb + e;
#pragma unroll
        for (int ni = 0; ni < 4; ++ni) {
          int col = n0 + (w & 1) * 64 + ni * 16 + lr;
          float v = acc[mi][ni][e];
          size_t idx = (size_t)row * N + col;
          if (EPI == 1) {
            ((float*)Cout)[idx] = resid[idx] + v + bias[col];
          } else if (EPI == 0) {
            ((__bf16*)Cout)[idx] = (__bf16)v;
          } else {  // EPI 4, sel==1: K row-major direct store
            int b = row >> 11, t2 = row & 2047;
            int cc = col & 1023, h = cc >> 6, d = cc & 63;
            int bh = b * 16 + h;
            k_out[((size_t)bh * 2048 + t2) * 64 + d] = (__bf16)v;
          }
        }
      }
    }
  }
}

// ---------------- causal flash attention v4 (dbuf staging) ------------------
// 4 waves/block, 32 q/wave (QBLK=128), KVBLK=64, double-buffered K/V LDS with
// counted vmcnt. Block handles q-tile pair (p, 15-p) -> uniform 34 kv-tiles.
// Grid (bh=64, p=8): same-bh blocks differ by 64 in flattened ID (≡0 mod 8)
// -> co-located on one XCD -> shared L2 copy of K/V.
// Qt: [BH][64][2048]  Kh: [BH][2048][64]  Vt: [BH][64][2048]  o: [B][T][1024]
__global__ __launch_bounds__(256) void attn_kernel4(const __bf16* __restrict__ Qt,
                                                    const __bf16* __restrict__ Kh,
                                                    const __bf16* __restrict__ Vt,
                                                    __bf16* __restrict__ o) {
  __shared__ __align__(16) char Klds[16384];  // 2 x 64 keys x 128B, swizzled
  __shared__ __align__(16) char Vlds[16384];  // 2 x 64 dims x 128B, swizzled
  int tid = threadIdx.x;
  int l = tid & 63, w = tid >> 6;
  int lq = l & 31, hi = l >> 5;
  int p = blockIdx.y, bh = blockIdx.x;
  int b = bh >> 4, h = bh & 15;

  const char* Kbase = (const char*)(Kh + (size_t)bh * 2048 * 64);
  const char* Vbase = (const char*)(Vt + (size_t)bh * 64 * 2048);
  const __bf16* Qbase = Qt + (size_t)bh * 64 * 2048;
  __bf16* Obase = o + (size_t)b * 2048 * 1024 + h * 64;

  int srow = tid >> 3;
  int schunk = (tid & 7) * 16;
  int sw0 = (srow & 7) << 4;
  int swz = (lq & 7) << 4;

  auto stageKV = [&](int bufi, int s0) {
    char* kd = Klds + bufi * 8192 + tid * 16;
    char* vd = Vlds + bufi * 8192 + tid * 16;
    gload_lds16(Kbase + (size_t)(s0 + srow) * 128 + (schunk ^ sw0), kd);
    gload_lds16(Kbase + (size_t)(s0 + srow + 32) * 128 + (schunk ^ sw0), kd + 4096);
    gload_lds16(Vbase + (size_t)srow * 4096 + s0 * 2 + (schunk ^ sw0), vd);
    gload_lds16(Vbase + (size_t)(srow + 32) * 4096 + s0 * 2 + (schunk ^ sw0), vd + 4096);
  };

  for (int sweep = 0; sweep < 2; ++sweep) {
    int t = (sweep == 0) ? p : 15 - p;
    int qw = t * 128 + w * 32;
    int qglob = qw + lq;

    // Q B-fragments: qb[s][j] = Q[hs = s*16 + hi*8 + j][qw + lq]
    bf16x8 qb[4];
    const __bf16* qsrc = Qbase + (size_t)(hi * 8) * 2048 + qw + lq;
#pragma unroll
    for (int s = 0; s < 4; ++s)
#pragma unroll
      for (int j = 0; j < 8; ++j)
        qb[s][j] = qsrc[(size_t)(s * 16 + j) * 2048];

    f32x16 oacc0, oacc1;
#pragma unroll
    for (int i = 0; i < 16; ++i) { oacc0[i] = 0.0f; oacc1[i] = 0.0f; }
    float m_q = -3.0e38f, l_q = 0.0f;

    int nkb = 2 * t + 2;
    stageKV(0, 0);
    for (int kb = 0; kb < nkb; ++kb) {
      int s0 = kb * 64;
      if (kb + 1 < nkb) { stageKV((kb + 1) & 1, s0 + 64); vm4(); }
      else vm0();
      bar();
      const char* Kb = Klds + (kb & 1) * 8192;
      const char* Vb = Vlds + (kb & 1) * 8192;

      if (s0 <= qw + 31) {  // else: tile fully masked for this wave
        f32x16 st0, st1;
#pragma unroll
        for (int i = 0; i < 16; ++i) { st0[i] = 0.0f; st1[i] = 0.0f; }
#pragma unroll
        for (int s = 0; s < 4; ++s) {
          bf16x8 ka = *(const bf16x8*)(Kb + lq * 128 + ((s * 32 + hi * 16) ^ swz));
          st0 = __builtin_amdgcn_mfma_f32_32x32x16_bf16(ka, qb[s], st0, 0, 0, 0);
        }
#pragma unroll
        for (int s = 0; s < 4; ++s) {
          bf16x8 ka = *(const bf16x8*)(Kb + (32 + lq) * 128 + ((s * 32 + hi * 16) ^ swz));
          st1 = __builtin_amdgcn_mfma_f32_32x32x16_bf16(ka, qb[s], st1, 0, 0, 0);
        }
        if (s0 + 63 > qw) {  // diagonal tiles only
#pragma unroll
          for (int r = 0; r < 16; ++r) {
            int key0 = s0 + (r & 3) + 8 * (r >> 2) + 4 * hi;
            if (key0 > qglob) st0[r] = -1.0e38f;
            if (key0 + 32 > qglob) st1[r] = -1.0e38f;
          }
        }
        float mx8[8];
#pragma unroll
        for (int i = 0; i < 8; ++i)
          mx8[i] = fmaxf(fmaxf(st0[i], st0[i + 8]), fmaxf(st1[i], st1[i + 8]));
        float mx = fmaxf(fmaxf(fmaxf(mx8[0], mx8[1]), fmaxf(mx8[2], mx8[3])),
                         fmaxf(fmaxf(mx8[4], mx8[5]), fmaxf(mx8[6], mx8[7])));
        {
          float u = mx, v = mx;
          asm("v_permlane32_swap_b32 %0, %1" : "+v"(u), "+v"(v));
          mx = fmaxf(u, v);
        }
        float mt_s = mx * 0.03125f;
        if (__any(mt_s > m_q + 8.0f)) {
          float mnew = fmaxf(m_q, mt_s);
          float scv = exp2f((m_q - mnew) * 1.44269504f);
          m_q = mnew;
          l_q *= scv;
#pragma unroll
          for (int r = 0; r < 16; ++r) {
            int qr = (r & 3) + 8 * (r >> 2) + 4 * hi;
            float scO = __shfl(scv, qr);
            oacc0[r] *= scO;
            oacc1[r] *= scO;
          }
        }
        float m2 = m_q * 1.44269504f;
#pragma unroll
        for (int r = 0; r < 16; ++r) {
          st0[r] = exp2f(fmaf(st0[r], 0.045084389f, -m2));
          st1[r] = exp2f(fmaf(st1[r], 0.045084389f, -m2));
        }
        float s8[8];
#pragma unroll
        for (int i = 0; i < 8; ++i)
          s8[i] = (st0[i] + st0[i + 8]) + (st1[i] + st1[i + 8]);
        float ps = ((s8[0] + s8[1]) + (s8[2] + s8[3])) +
                   ((s8[4] + s8[5]) + (s8[6] + s8[7]));
        {
          float u = ps, v = ps;
          asm("v_permlane32_swap_b32 %0, %1" : "+v"(u), "+v"(v));
          ps = u + v;
        }
        l_q += ps;

        {
          unsigned int w0 = cvt_pk(st0[0], st0[1]), w1 = cvt_pk(st0[2], st0[3]);
          unsigned int w2 = cvt_pk(st0[4], st0[5]), w3 = cvt_pk(st0[6], st0[7]);
          asm("v_permlane32_swap_b32 %0, %1" : "+v"(w0), "+v"(w2));
          asm("v_permlane32_swap_b32 %0, %1" : "+v"(w1), "+v"(w3));
          bf16x8 pa0 = pack_frag(w0, w1, w2, w3);
          unsigned int w4 = cvt_pk(st0[8], st0[9]), w5 = cvt_pk(st0[10], st0[11]);
          unsigned int w6 = cvt_pk(st0[12], st0[13]), w7 = cvt_pk(st0[14], st0[15]);
          asm("v_permlane32_swap_b32 %0, %1" : "+v"(w4), "+v"(w6));
          asm("v_permlane32_swap_b32 %0, %1" : "+v"(w5), "+v"(w7));
          bf16x8 pa1 = pack_frag(w4, w5, w6, w7);
          bf16x8 v00 = *(const bf16x8*)(Vb + lq * 128 + ((hi * 16) ^ swz));
          bf16x8 v01 = *(const bf16x8*)(Vb + (32 + lq) * 128 + ((hi * 16) ^ swz));
          bf16x8 v10 = *(const bf16x8*)(Vb + lq * 128 + ((32 + hi * 16) ^ swz));
          bf16x8 v11 = *(const bf16x8*)(Vb + (32 + lq) * 128 + ((32 + hi * 16) ^ swz));
          oacc0 = __builtin_amdgcn_mfma_f32_32x32x16_bf16(pa0, v00, oacc0, 0, 0, 0);
          oacc1 = __builtin_amdgcn_mfma_f32_32x32x16_bf16(pa0, v01, oacc1, 0, 0, 0);
          oacc0 = __builtin_amdgcn_mfma_f32_32x32x16_bf16(pa1, v10, oacc0, 0, 0, 0);
          oacc1 = __builtin_amdgcn_mfma_f32_32x32x16_bf16(pa1, v11, oacc1, 0, 0, 0);
        }
        {
          unsigned int w0 = cvt_pk(st1[0], st1[1]), w1 = cvt_pk(st1[2], st1[3]);
          unsigned int w2 = cvt_pk(st1[4], st1[5]), w3 = cvt_pk(st1[6], st1[7]);
          asm("v_permlane32_swap_b32 %0, %1" : "+v"(w0), "+v"(w2));
          asm("v_permlane32_swap_b32 %0, %1" : "+v"(w1), "+v"(w3));
          bf16x8 pa0 = pack_frag(w0, w1, w2, w3);
          unsigned int w4 = cvt_pk(st1[8], st1[9]), w5 = cvt_pk(st1[10], st1[11]);
          unsigned int w6 = cvt_pk(st1[12], st1[13]), w7 = cvt_pk(st1[14], st1[15]);
          asm("v_permlane32_swap_b32 %0, %1" : "+v"(w4), "+v"(w6));
          asm("v_permlane32_swap_b32 %0, %1" : "+v"(w5), "+v"(w7));
          bf16x8 pa1 = pack_frag(w4, w5, w6, w7);
          bf16x8 v00 = *(const bf16x8*)(Vb + lq * 128 + ((64 + hi * 16) ^ swz));
          bf16x8 v01 = *(const bf16x8*)(Vb + (32 + lq) * 128 + ((64 + hi * 16) ^ swz));
          bf16x8 v10 = *(const bf16x8*)(Vb + lq * 128 + ((96 + hi * 16) ^ swz));
          bf16x8 v11 = *(const bf16x8*)(Vb + (32 + lq) * 128 + ((96 + hi * 16) ^ swz));
          oacc0 = __builtin_amdgcn_mfma_f32_32x32x16_bf16(pa0, v00, oacc0, 0, 0, 0);
          oacc1 = __builtin_amdgcn_mfma_f32_32x32x16_bf16(pa0, v01, oacc1, 0, 0, 0);
          oacc0 = __builtin_amdgcn_mfma_f32_32x32x16_bf16(pa1, v10, oacc0, 0, 0, 0);
          oacc1 = __builtin_amdgcn_mfma_f32_32x32x16_bf16(pa1, v11, oacc1, 0, 0, 0);
        }
      }
      bar();
    }
#pragma unroll
    for (int r = 0; r < 16; ++r) {
      int qr = (r & 3) + 8 * (r >> 2) + 4 * hi;
      float linv = 1.0f / __shfl(l_q, qr);
      size_t row = qw + qr;
      Obase[row * 1024 + lq] = (__bf16)(oacc0[r] * linv);
      Obase[row * 1024 + 32 + lq] = (__bf16)(oacc1[r] * linv);
    }
  }
}

// ---------------- launcher ----------------
extern "C" void kernel_launch(void* const* d_in, const int* in_sizes, int n_in,
                              void* d_out, int out_size, void* d_ws, size_t ws_size,
                              hipStream_t stream) {
  const float* x     = (const float*)d_in[0];
  const float* Wq    = (const float*)d_in[1];
  const float* Wk    = (const float*)d_in[2];
  const float* Wv    = (const float*)d_in[3];
  const float* Wproj = (const float*)d_in[4];
  const float* bproj = (const float*)d_in[5];
  const float* ln1_g = (const float*)d_in[6];
  const float* ln1_b = (const float*)d_in[7];
  const float* ln2_g = (const float*)d_in[8];
  const float* ln2_b = (const float*)d_in[9];
  const float* W1    = (const float*)d_in[10];
  const float* b1    = (const float*)d_in[11];
  const float* W2    = (const float*)d_in[12];
  const float* b2    = (const float*)d_in[13];
  float* out = (float*)d_out;

  char* ws = (char*)d_ws;
  __bf16* actA   = (__bf16*)(ws + 0);          // 16 MB (ln1 out, then ln2 out)
  __bf16* WqkvT  = (__bf16*)(ws + 16777216);   // 6 MB
  __bf16* WprojT = (__bf16*)(ws + 23068672);   // 2 MB
  __bf16* W1T    = (__bf16*)(ws + 25165824);   // 8 MB
  __bf16* W2T    = (__bf16*)(ws + 33554432);   // 8 MB
  __bf16* Qt     = (__bf16*)(ws + 41943040);   // 16 MB [BH][64][2048]
  __bf16* Kh     = (__bf16*)(ws + 58720256);   // 16 MB [BH][2048][64]
  __bf16* Vt     = (__bf16*)(ws + 75497472);   // 16 MB [BH][64][2048]
  __bf16* obuf   = (__bf16*)(ws + 92274688);   // 16 MB
  __bf16* ff1    = Qt;                         // 64 MB (Qt..obuf dead by then)
  __bf16* p0     = (__bf16*)(ws + 0);          // 16 MB (actA dead after FF1)
  __bf16* p1     = (__bf16*)(ws + 16777216);   // 16 MB (weights dead by FF2)

  dim3 t32x8(32, 8);
  qkv_repack<<<dim3(2, 32, 48), t32x8, 0, stream>>>(Wq, Wk, Wv, WqkvT);
  transpose_cvt<<<dim3(32, 32), t32x8, 0, stream>>>(Wproj, WprojT, 1024, 1024);
  transpose_cvt<<<dim3(128, 32), t32x8, 0, stream>>>(W1, W1T, 1024, 4096);
  transpose_cvt<<<dim3(32, 128), t32x8, 0, stream>>>(W2, W2T, 4096, 1024);

  ln_kernel<<<8192, 256, 0, stream>>>(x, ln1_g, ln1_b, actA);
  gemm2p<4><<<dim3(1536, 1, 1), 256, 0, stream>>>(actA, WqkvT, nullptr, nullptr, nullptr,
                                                  Qt, Kh, Vt, 8192, 3072, 1024, 24);
  attn_kernel4<<<dim3(64, 8), 256, 0, stream>>>(Qt, Kh, Vt, obuf);
  gemm2p<1><<<dim3(512, 1, 1), 256, 0, stream>>>(obuf, WprojT, out, bproj, x,
                                                 nullptr, nullptr, nullptr, 8192, 1024, 1024, 8);
  ln_kernel<<<8192, 256, 0, stream>>>(out, ln2_g, ln2_b, actA);
  gemm8p<2><<<dim3(512, 1, 1), 512, 0, stream>>>(actA, W1T, ff1, b1, nullptr,
                                                 nullptr, nullptr, nullptr, 8192, 4096, 1024, 16);
  gemm8p<5><<<dim3(128, 1, 2), 512, 0, stream>>>(ff1, W2T, nullptr, nullptr, nullptr,
                                                 p0, p1, nullptr, 8192, 1024, 4096, 4);
  ff2_reduce<<<8192, 256, 0, stream>>>(out, p0, p1, b2);
}